// Round 2
// baseline (2895.003 us; speedup 1.0000x reference)
//
#include <hip/hip_runtime.h>
#include <hip/hip_bf16.h>
#include <math.h>

constexpr int N_NODES = 150000;
constexpr int N_EDGES = 1200000;
constexpr int NPGC    = 30;
constexpr int NGRAPH  = N_NODES / NPGC;

__device__ __forceinline__ float lrelu(float v) { return v > 0.f ? v : 0.2f * v; }

__device__ float atomicMaxF(float* addr, float val) {
  int* ia = (int*)addr;
  int old = *ia;
  while (__int_as_float(old) < val) {
    int assumed = old;
    old = atomicCAS(ia, assumed, __float_as_int(val));
    if (old == assumed) break;
  }
  return __int_as_float(old);
}

// red layout: [0..2] colsum, [3..5] colmax, [6] softmax max, [7] softmax sumexp
__global__ void k_init(float* red) {
  int t = threadIdx.x;
  if (t < 3) red[t] = 0.f;
  else if (t < 7) red[t] = -INFINITY;
  else if (t == 7) red[t] = 0.f;
}

__global__ void k_colstats(const float* __restrict__ x, float* __restrict__ red, int n) {
  float s0 = 0, s1 = 0, s2 = 0;
  float m0 = -INFINITY, m1 = -INFINITY, m2 = -INFINITY;
  for (int i = blockIdx.x * blockDim.x + threadIdx.x; i < n; i += gridDim.x * blockDim.x) {
    float v0 = x[3 * i], v1 = x[3 * i + 1], v2 = x[3 * i + 2];
    s0 += v0; s1 += v1; s2 += v2;
    m0 = fmaxf(m0, v0); m1 = fmaxf(m1, v1); m2 = fmaxf(m2, v2);
  }
  for (int o = 32; o > 0; o >>= 1) {
    s0 += __shfl_down(s0, o); s1 += __shfl_down(s1, o); s2 += __shfl_down(s2, o);
    m0 = fmaxf(m0, __shfl_down(m0, o));
    m1 = fmaxf(m1, __shfl_down(m1, o));
    m2 = fmaxf(m2, __shfl_down(m2, o));
  }
  if ((threadIdx.x & 63) == 0) {
    atomicAdd(&red[0], s0); atomicAdd(&red[1], s1); atomicAdd(&red[2], s2);
    atomicMaxF(&red[3], m0); atomicMaxF(&red[4], m1); atomicMaxF(&red[5], m2);
  }
}

__global__ void k_norm(const float* __restrict__ x, const float* __restrict__ red,
                       float* __restrict__ x0, int n) {
  int i = blockIdx.x * 256 + threadIdx.x;
  if (i >= n * 3) return;
  int c = i % 3;
  float mean = red[c] / (float)n;
  float denom = red[3 + c] - mean;   // max(x - mean) = max(x) - mean
  x0[i] = (x[i] - mean) / denom;
}

// layer-1 scatter: FIN=3, agg lives in h1 rows (stride 64): [0:3]=gcn agg, [3:6]=gin agg
__global__ void k_scatter3(const float* __restrict__ x0, const int* __restrict__ row,
                           const int* __restrict__ col, const float* __restrict__ ew,
                           float* __restrict__ agg, int ne) {
  int e = blockIdx.x * 256 + threadIdx.x;
  if (e >= ne) return;
  int r = row[e], c = col[e];
  float w = ew[e];
  float v0 = x0[r * 3], v1 = x0[r * 3 + 1], v2 = x0[r * 3 + 2];
  float* ap = agg + (size_t)c * 64;
  atomicAdd(ap + 0, v0 * w); atomicAdd(ap + 1, v1 * w); atomicAdd(ap + 2, v2 * w);
  atomicAdd(ap + 3, v0);     atomicAdd(ap + 4, v1);     atomicAdd(ap + 5, v2);
}

// wide scatter: one thread per (edge, feature). agg rows stride 2*FIN.
template <int FIN>
__global__ __launch_bounds__(256) void k_scatter_wide(
    const float* __restrict__ h, const int* __restrict__ row, const int* __restrict__ col,
    const float* __restrict__ ew, float* __restrict__ agg, int ne) {
  constexpr int STRIDE = 2 * FIN;
  int gid = blockIdx.x * 256 + threadIdx.x;
  int e = gid / FIN;
  if (e >= ne) return;
  int f = gid % FIN;
  int r = row[e], c = col[e];
  float v = h[(size_t)r * FIN + f];
  float w = ew[e];
  atomicAdd(&agg[(size_t)c * STRIDE + f], v * w);
  atomicAdd(&agg[(size_t)c * STRIDE + FIN + f], v);
}

// fused node update: GCN linear + GIN 2-layer MLP + lrelu(concat), in place over h_next.
// h_next rows (stride 2*FOUT) come in holding [aggA | aggB] in [0:2*FIN).
template <int FIN, int FOUT, int UN>
__global__ __launch_bounds__(256) void k_node(
    const float* __restrict__ h_prev, float* __restrict__ h_next,
    const float* __restrict__ gw, const float* __restrict__ gb,
    const float* __restrict__ w1, const float* __restrict__ b1,
    const float* __restrict__ w2, const float* __restrict__ b2,
    const float* __restrict__ epsp, int n) {
  constexpr int STRIDE = 2 * FOUT;
  constexpr int G = 256 / STRIDE;     // thread groups per block
  constexpr int NPB = G * UN;         // nodes per block-iteration
  __shared__ float W[FIN * FOUT];
  __shared__ float W1s[FIN * 10];
  __shared__ float W2s[10 * FOUT];
  __shared__ float GB[FOUT];
  __shared__ float B1[10];
  __shared__ float B2[FOUT];
  __shared__ float AGG[NPB][FIN];
  __shared__ float M[NPB][FIN];
  __shared__ float T[NPB][10];
  const int tid = threadIdx.x;
  for (int i = tid; i < FIN * FOUT; i += 256) W[i] = gw[i];
  for (int i = tid; i < FIN * 10; i += 256) W1s[i] = w1[i];
  for (int i = tid; i < 10 * FOUT; i += 256) W2s[i] = w2[i];
  for (int i = tid; i < FOUT; i += 256) { GB[i] = gb[i]; B2[i] = b2[i]; }
  if (tid < 10) B1[tid] = b1[tid];
  const float eps1 = 1.0f + epsp[0];
  const int g = tid / STRIDE;
  const int j = tid % STRIDE;
  for (int base = blockIdx.x * NPB; base < n; base += gridDim.x * NPB) {
    __syncthreads();
    for (int i = tid; i < NPB * FIN; i += 256) {
      int nd = i / FIN, f = i % FIN;
      int node = base + nd;
      if (node < n) {
        AGG[nd][f] = h_next[(size_t)node * STRIDE + f];
        M[nd][f] = eps1 * h_prev[(size_t)node * FIN + f] + h_next[(size_t)node * STRIDE + FIN + f];
      }
    }
    __syncthreads();
    if (tid < NPB * 16) {
      int nd = tid >> 4, k = tid & 15;
      if (k < 10 && base + nd < n) {
        float acc = B1[k];
        #pragma unroll 4
        for (int f = 0; f < FIN; ++f) acc += M[nd][f] * W1s[f * 10 + k];
        T[nd][k] = fmaxf(acc, 0.f);
      }
    }
    __syncthreads();
    float acc[UN];
    const int nd0 = g * UN;
    if (j < FOUT) {
      #pragma unroll
      for (int u = 0; u < UN; ++u) acc[u] = GB[j];
      for (int f = 0; f < FIN; ++f) {
        float wv = W[f * FOUT + j];
        #pragma unroll
        for (int u = 0; u < UN; ++u) acc[u] += AGG[nd0 + u][f] * wv;
      }
      #pragma unroll
      for (int u = 0; u < UN; ++u) {
        int node = base + nd0 + u;
        if (node < n) h_next[(size_t)node * STRIDE + j] = lrelu(acc[u]);
      }
    } else {
      int jj = j - FOUT;
      #pragma unroll
      for (int u = 0; u < UN; ++u) acc[u] = B2[jj];
      #pragma unroll
      for (int k = 0; k < 10; ++k) {
        float wv = W2s[k * FOUT + jj];
        #pragma unroll
        for (int u = 0; u < UN; ++u) acc[u] += T[nd0 + u][k] * wv;
      }
      #pragma unroll
      for (int u = 0; u < UN; ++u) {
        int node = base + nd0 + u;
        if (node < n) h_next[(size_t)node * STRIDE + j] = lrelu(fmaxf(acc[u], 0.f));
      }
    }
  }
}

// hj[n] = dot(h3[n,:256], gat_w) ; one 64-lane wave per node
__global__ __launch_bounds__(256) void k_hj(const float* __restrict__ h3,
                                            const float* __restrict__ gw,
                                            float* __restrict__ hj, int n) {
  int wid = blockIdx.x * 4 + (threadIdx.x >> 6);
  int lane = threadIdx.x & 63;
  if (wid >= n) return;
  const float* r = h3 + (size_t)wid * 256;
  float acc = r[lane] * gw[lane] + r[lane + 64] * gw[lane + 64] +
              r[lane + 128] * gw[lane + 128] + r[lane + 192] * gw[lane + 192];
  for (int o = 32; o > 0; o >>= 1) acc += __shfl_down(acc, o);
  if (lane == 0) hj[wid] = acc;
}

__global__ void k_edge_max(const int* __restrict__ row, const float* __restrict__ hj,
                           const float* __restrict__ att, float* __restrict__ red, int ne) {
  float a = att[0];
  float m = -INFINITY;
  for (int e = blockIdx.x * blockDim.x + threadIdx.x; e < ne; e += gridDim.x * blockDim.x) {
    m = fmaxf(m, lrelu(a * hj[row[e]]));
  }
  for (int o = 32; o > 0; o >>= 1) m = fmaxf(m, __shfl_down(m, o));
  if ((threadIdx.x & 63) == 0) atomicMaxF(&red[6], m);
}

__global__ void k_edge_exp(const int* __restrict__ row, const int* __restrict__ col,
                           const float* __restrict__ hj, const float* __restrict__ att,
                           float* __restrict__ red, float* __restrict__ scat, int ne) {
  float a = att[0];
  float m = red[6];
  float lsum = 0.f;
  for (int e = blockIdx.x * blockDim.x + threadIdx.x; e < ne; e += gridDim.x * blockDim.x) {
    float hjr = hj[row[e]];
    float p = expf(lrelu(a * hjr) - m);
    lsum += p;
    atomicAdd(&scat[col[e]], p * hjr);
  }
  for (int o = 32; o > 0; o >>= 1) lsum += __shfl_down(lsum, o);
  if ((threadIdx.x & 63) == 0) atomicAdd(&red[7], lsum);
}

// mean-pool (weighted by att) + 256->10->1 MLP + sigmoid. One block per graph.
__global__ __launch_bounds__(256) void k_pool(
    const float* __restrict__ h3, const float* __restrict__ scat, const float* __restrict__ red,
    const float* __restrict__ lw, const float* __restrict__ lb,
    const float* __restrict__ l2w, const float* __restrict__ l2b,
    float* __restrict__ out, int ng) {
  __shared__ float pooled[256];
  __shared__ float aw[NPGC];
  __shared__ float y[10];
  int g = blockIdx.x;
  if (g >= ng) return;
  int tid = threadIdx.x;
  float inv_sexp = 1.0f / red[7];
  if (tid < NPGC) aw[tid] = scat[g * NPGC + tid] * inv_sexp;
  __syncthreads();
  const float* base = h3 + (size_t)g * NPGC * 256;
  float acc = 0.f;
  #pragma unroll
  for (int u = 0; u < NPGC; ++u) acc += base[u * 256 + tid] * aw[u];
  pooled[tid] = acc * (1.0f / NPGC);
  __syncthreads();
  if (tid < 10) {
    float s = lb[tid];
    for (int f = 0; f < 256; ++f) s += pooled[f] * lw[f * 10 + tid];
    y[tid] = s;
  }
  __syncthreads();
  if (tid == 0) {
    float s = l2b[0];
    #pragma unroll
    for (int k = 0; k < 10; ++k) s += y[k] * l2w[k];
    out[g] = 1.0f / (1.0f + expf(-s));
  }
}

extern "C" void kernel_launch(void* const* d_in, const int* in_sizes, int n_in,
                              void* d_out, int out_size, void* d_ws, size_t ws_size,
                              hipStream_t stream) {
  const float* x        = (const float*)d_in[0];
  const int*   eidx     = (const int*)d_in[1];
  const float* ew       = (const float*)d_in[2];
  const float* gcn1_w   = (const float*)d_in[3];
  const float* gcn1_b   = (const float*)d_in[4];
  const float* gcn2_w   = (const float*)d_in[5];
  const float* gcn2_b   = (const float*)d_in[6];
  const float* gcn3_w   = (const float*)d_in[7];
  const float* gcn3_b   = (const float*)d_in[8];
  const float* gin1_w1  = (const float*)d_in[9];
  const float* gin1_b1  = (const float*)d_in[10];
  const float* gin1_w2  = (const float*)d_in[11];
  const float* gin1_b2  = (const float*)d_in[12];
  const float* gin1_eps = (const float*)d_in[13];
  const float* gin2_w1  = (const float*)d_in[14];
  const float* gin2_b1  = (const float*)d_in[15];
  const float* gin2_w2  = (const float*)d_in[16];
  const float* gin2_b2  = (const float*)d_in[17];
  const float* gin2_eps = (const float*)d_in[18];
  const float* gin3_w1  = (const float*)d_in[19];
  const float* gin3_b1  = (const float*)d_in[20];
  const float* gin3_w2  = (const float*)d_in[21];
  const float* gin3_b2  = (const float*)d_in[22];
  const float* gin3_eps = (const float*)d_in[23];
  const float* gat_w    = (const float*)d_in[24];
  const float* gat_att  = (const float*)d_in[25];
  const float* lin_w    = (const float*)d_in[26];
  const float* lin_b    = (const float*)d_in[27];
  const float* lin2_w   = (const float*)d_in[28];
  const float* lin2_b   = (const float*)d_in[29];
  float* out = (float*)d_out;

  const int* row = eidx;
  const int* col = eidx + N_EDGES;

  // Time-multiplexed workspace (peak = N*384 + 64 floats = 230.4 MB):
  //  P3 [N*256]: h1 (first N*64, layers 1-2) -> layer-3 agg + h3 (layer 3 .. pool)
  //  P2 [N*128]: x0 (first N*3, layer 1)     -> layer-2 agg + h2 -> hj [0:N] + scat [N:2N]
  //  red [64] at the end.
  // Safe because the stream serializes each region's last reader before the
  // next phase's memset: x0 dies at node1, h1 dies at node2, h2 dies at node3.
  float* ws   = (float*)d_ws;
  float* P3   = ws;                          // N*256
  float* P2   = ws + (size_t)N_NODES * 256;  // N*128
  float* red  = ws + (size_t)N_NODES * 384;  // 64

  float* x0   = P2;   // N*3, dies after node1
  float* h1   = P3;   // N*64, dies after node2
  float* h2   = P2;   // N*128, dies after node3
  float* h3   = P3;   // N*256, lives to the end
  float* hj   = P2;                  // N, born after node3
  float* scat = P2 + N_NODES;        // N

  // normalization
  hipLaunchKernelGGL(k_init, dim3(1), dim3(64), 0, stream, red);
  hipLaunchKernelGGL(k_colstats, dim3(256), dim3(256), 0, stream, x, red, N_NODES);
  hipLaunchKernelGGL(k_norm, dim3((N_NODES * 3 + 255) / 256), dim3(256), 0, stream,
                     x, red, x0, N_NODES);

  // layer 1: 3 -> 32|32
  hipMemsetAsync(h1, 0, (size_t)N_NODES * 64 * 4, stream);
  hipLaunchKernelGGL(k_scatter3, dim3((N_EDGES + 255) / 256), dim3(256), 0, stream,
                     x0, row, col, ew, h1, N_EDGES);
  hipLaunchKernelGGL((k_node<3, 32, 4>), dim3(512), dim3(256), 0, stream,
                     x0, h1, gcn1_w, gcn1_b, gin1_w1, gin1_b1, gin1_w2, gin1_b2, gin1_eps, N_NODES);

  // layer 2: 64 -> 64|64
  hipMemsetAsync(h2, 0, (size_t)N_NODES * 128 * 4, stream);
  {
    long long total = (long long)N_EDGES * 64;
    hipLaunchKernelGGL((k_scatter_wide<64>), dim3((int)((total + 255) / 256)), dim3(256), 0, stream,
                       h1, row, col, ew, h2, N_EDGES);
  }
  hipLaunchKernelGGL((k_node<64, 64, 4>), dim3(512), dim3(256), 0, stream,
                     h1, h2, gcn2_w, gcn2_b, gin2_w1, gin2_b1, gin2_w2, gin2_b2, gin2_eps, N_NODES);

  // layer 3: 128 -> 128|128
  hipMemsetAsync(h3, 0, (size_t)N_NODES * 256 * 4, stream);
  {
    long long total = (long long)N_EDGES * 128;
    hipLaunchKernelGGL((k_scatter_wide<128>), dim3((int)((total + 255) / 256)), dim3(256), 0, stream,
                       h2, row, col, ew, h3, N_EDGES);
  }
  hipLaunchKernelGGL((k_node<128, 128, 4>), dim3(512), dim3(256), 0, stream,
                     h2, h3, gcn3_w, gcn3_b, gin3_w1, gin3_b1, gin3_w2, gin3_b2, gin3_eps, N_NODES);

  // GAT (h2 is dead now; hj/scat reuse P2)
  hipLaunchKernelGGL(k_hj, dim3((N_NODES + 3) / 4), dim3(256), 0, stream, h3, gat_w, hj, N_NODES);
  hipLaunchKernelGGL(k_edge_max, dim3(1024), dim3(256), 0, stream, row, hj, gat_att, red, N_EDGES);
  hipMemsetAsync(scat, 0, (size_t)N_NODES * 4, stream);
  hipLaunchKernelGGL(k_edge_exp, dim3(1024), dim3(256), 0, stream, row, col, hj, gat_att, red, scat, N_EDGES);

  // pool + readout
  hipLaunchKernelGGL(k_pool, dim3(NGRAPH), dim3(256), 0, stream,
                     h3, scat, red, lin_w, lin_b, lin2_w, lin2_b, out, NGRAPH);
}

// Round 3
// 2186.961 us; speedup vs baseline: 1.3238x; 1.3238x over previous
//
#include <hip/hip_runtime.h>
#include <hip/hip_bf16.h>
#include <math.h>

constexpr int N_NODES = 150000;
constexpr int N_EDGES = 1200000;
constexpr int NPGC    = 30;
constexpr int NGRAPH  = N_NODES / NPGC;
constexpr int NB_SCAN = (N_NODES + 1023) / 1024;   // 147 scan blocks

__device__ __forceinline__ float lrelu(float v) { return v > 0.f ? v : 0.2f * v; }

__device__ float atomicMaxF(float* addr, float val) {
  int* ia = (int*)addr;
  int old = *ia;
  while (__int_as_float(old) < val) {
    int assumed = old;
    old = atomicCAS(ia, assumed, __float_as_int(val));
    if (old == assumed) break;
  }
  return __int_as_float(old);
}

// ---------------- CSR build (per launch; deterministic rebuild) ----------------

__global__ void k_degree(const int* __restrict__ col, int* __restrict__ deg, int ne) {
  int e = blockIdx.x * 256 + threadIdx.x;
  if (e < ne) atomicAdd(&deg[col[e]], 1);
}

// pass 1: per-block (1024 items) exclusive scan -> rowptr, block totals -> bsum
__global__ __launch_bounds__(256) void k_scan1(const int* __restrict__ deg,
                                               int* __restrict__ rowptr,
                                               int* __restrict__ bsum, int n) {
  __shared__ int ts[256];
  int b = blockIdx.x, tid = threadIdx.x;
  int base = b * 1024 + tid * 4;
  int d[4]; int s = 0;
  #pragma unroll
  for (int k = 0; k < 4; ++k) { d[k] = (base + k < n) ? deg[base + k] : 0; s += d[k]; }
  ts[tid] = s;
  __syncthreads();
  for (int off = 1; off < 256; off <<= 1) {
    int v = (tid >= off) ? ts[tid - off] : 0;
    __syncthreads();
    ts[tid] += v;
    __syncthreads();
  }
  int run = ts[tid] - s;  // exclusive offset within block
  #pragma unroll
  for (int k = 0; k < 4; ++k) {
    if (base + k < n) rowptr[base + k] = run;
    run += d[k];
  }
  if (tid == 255) bsum[b] = ts[255];
}

// pass 2: single block turns bsum into exclusive scan (nb <= 256)
__global__ __launch_bounds__(256) void k_scan2(int* __restrict__ bsum, int nb) {
  __shared__ int ts[256];
  int tid = threadIdx.x;
  int orig = (tid < nb) ? bsum[tid] : 0;
  ts[tid] = orig;
  __syncthreads();
  for (int off = 1; off < 256; off <<= 1) {
    int v = (tid >= off) ? ts[tid - off] : 0;
    __syncthreads();
    ts[tid] += v;
    __syncthreads();
  }
  if (tid < nb) bsum[tid] = ts[tid] - orig;
}

// pass 3: add block offsets
__global__ void k_scan3(int* __restrict__ rowptr, const int* __restrict__ bsum, int n) {
  int i = blockIdx.x * 256 + threadIdx.x;
  if (i < n) rowptr[i] += bsum[i >> 10];
}

// fill: rowptr doubles as cursor; afterwards rowptr[c] == end(c), start(c)=rowptr[c-1]
__global__ void k_fill(const int* __restrict__ row, const int* __restrict__ col,
                       const float* __restrict__ ew, int* __restrict__ rowptr,
                       int* __restrict__ csr_row, float* __restrict__ csr_w, int ne) {
  int e = blockIdx.x * 256 + threadIdx.x;
  if (e >= ne) return;
  int c = col[e];
  int p = atomicAdd(&rowptr[c], 1);
  csr_row[p] = row[e];
  csr_w[p] = ew[e];
}

// ---------------- input normalization ----------------

// red layout: [0..2] colsum, [3..5] colmax, [6] softmax max, [7] softmax sumexp
__global__ void k_init(float* red) {
  int t = threadIdx.x;
  if (t < 3) red[t] = 0.f;
  else if (t < 7) red[t] = -INFINITY;
  else if (t == 7) red[t] = 0.f;
}

__global__ void k_colstats(const float* __restrict__ x, float* __restrict__ red, int n) {
  float s0 = 0, s1 = 0, s2 = 0;
  float m0 = -INFINITY, m1 = -INFINITY, m2 = -INFINITY;
  for (int i = blockIdx.x * blockDim.x + threadIdx.x; i < n; i += gridDim.x * blockDim.x) {
    float v0 = x[3 * i], v1 = x[3 * i + 1], v2 = x[3 * i + 2];
    s0 += v0; s1 += v1; s2 += v2;
    m0 = fmaxf(m0, v0); m1 = fmaxf(m1, v1); m2 = fmaxf(m2, v2);
  }
  for (int o = 32; o > 0; o >>= 1) {
    s0 += __shfl_down(s0, o); s1 += __shfl_down(s1, o); s2 += __shfl_down(s2, o);
    m0 = fmaxf(m0, __shfl_down(m0, o));
    m1 = fmaxf(m1, __shfl_down(m1, o));
    m2 = fmaxf(m2, __shfl_down(m2, o));
  }
  if ((threadIdx.x & 63) == 0) {
    atomicAdd(&red[0], s0); atomicAdd(&red[1], s1); atomicAdd(&red[2], s2);
    atomicMaxF(&red[3], m0); atomicMaxF(&red[4], m1); atomicMaxF(&red[5], m2);
  }
}

__global__ void k_norm(const float* __restrict__ x, const float* __restrict__ red,
                       float* __restrict__ x0, int n) {
  int i = blockIdx.x * 256 + threadIdx.x;
  if (i >= n * 3) return;
  int c = i % 3;
  float mean = red[c] / (float)n;
  float denom = red[3 + c] - mean;   // max(x - mean) = max(x) - mean
  x0[i] = (x[i] - mean) / denom;
}

// ---------------- layer 1 (FIN=3): CSR gather into h1 agg slots ----------------

__global__ void k_gather3(const float* __restrict__ x0, const int* __restrict__ rend,
                          const int* __restrict__ csr_row, const float* __restrict__ csr_w,
                          float* __restrict__ h1, int n) {
  int c = blockIdx.x * 256 + threadIdx.x;
  if (c >= n) return;
  int s = (c == 0) ? 0 : rend[c - 1];
  int e = rend[c];
  float a0 = 0, a1 = 0, a2 = 0, b0 = 0, b1 = 0, b2 = 0;
  for (int p = s; p < e; ++p) {
    int r = csr_row[p];
    float w = csr_w[p];
    float v0 = x0[3 * r], v1 = x0[3 * r + 1], v2 = x0[3 * r + 2];
    a0 += v0 * w; a1 += v1 * w; a2 += v2 * w;
    b0 += v0; b1 += v1; b2 += v2;
  }
  float* ap = h1 + (size_t)c * 64;
  ap[0] = a0; ap[1] = a1; ap[2] = a2; ap[3] = b0; ap[4] = b1; ap[5] = b2;
}

// fused node update (layer 1): GCN linear + GIN MLP + lrelu concat, in place on h1.
template <int FIN, int FOUT, int UN>
__global__ __launch_bounds__(256) void k_node(
    const float* __restrict__ h_prev, float* __restrict__ h_next,
    const float* __restrict__ gw, const float* __restrict__ gb,
    const float* __restrict__ w1, const float* __restrict__ b1,
    const float* __restrict__ w2, const float* __restrict__ b2,
    const float* __restrict__ epsp, int n) {
  constexpr int STRIDE = 2 * FOUT;
  constexpr int G = 256 / STRIDE;
  constexpr int NPB = G * UN;
  __shared__ float W[FIN * FOUT];
  __shared__ float W1s[FIN * 10];
  __shared__ float W2s[10 * FOUT];
  __shared__ float GB[FOUT];
  __shared__ float B1[10];
  __shared__ float B2[FOUT];
  __shared__ float AGG[NPB][FIN];
  __shared__ float M[NPB][FIN + 2];
  __shared__ float T[NPB][10];
  const int tid = threadIdx.x;
  for (int i = tid; i < FIN * FOUT; i += 256) W[i] = gw[i];
  for (int i = tid; i < FIN * 10; i += 256) W1s[i] = w1[i];
  for (int i = tid; i < 10 * FOUT; i += 256) W2s[i] = w2[i];
  for (int i = tid; i < FOUT; i += 256) { GB[i] = gb[i]; B2[i] = b2[i]; }
  if (tid < 10) B1[tid] = b1[tid];
  const float eps1 = 1.0f + epsp[0];
  const int g = tid / STRIDE;
  const int j = tid % STRIDE;
  for (int base = blockIdx.x * NPB; base < n; base += gridDim.x * NPB) {
    __syncthreads();
    for (int i = tid; i < NPB * FIN; i += 256) {
      int nd = i / FIN, f = i % FIN;
      int node = base + nd;
      if (node < n) {
        AGG[nd][f] = h_next[(size_t)node * STRIDE + f];
        M[nd][f] = eps1 * h_prev[(size_t)node * FIN + f] + h_next[(size_t)node * STRIDE + FIN + f];
      }
    }
    __syncthreads();
    if (tid < NPB * 16) {
      int nd = tid >> 4, k = tid & 15;
      if (k < 10 && base + nd < n) {
        float acc = B1[k];
        #pragma unroll 4
        for (int f = 0; f < FIN; ++f) acc += M[nd][f] * W1s[f * 10 + k];
        T[nd][k] = fmaxf(acc, 0.f);
      }
    }
    __syncthreads();
    float acc[UN];
    const int nd0 = g * UN;
    if (j < FOUT) {
      #pragma unroll
      for (int u = 0; u < UN; ++u) acc[u] = GB[j];
      for (int f = 0; f < FIN; ++f) {
        float wv = W[f * FOUT + j];
        #pragma unroll
        for (int u = 0; u < UN; ++u) acc[u] += AGG[nd0 + u][f] * wv;
      }
      #pragma unroll
      for (int u = 0; u < UN; ++u) {
        int node = base + nd0 + u;
        if (node < n) h_next[(size_t)node * STRIDE + j] = lrelu(acc[u]);
      }
    } else {
      int jj = j - FOUT;
      #pragma unroll
      for (int u = 0; u < UN; ++u) acc[u] = B2[jj];
      #pragma unroll
      for (int k = 0; k < 10; ++k) {
        float wv = W2s[k * FOUT + jj];
        #pragma unroll
        for (int u = 0; u < UN; ++u) acc[u] += T[nd0 + u][k] * wv;
      }
      #pragma unroll
      for (int u = 0; u < UN; ++u) {
        int node = base + nd0 + u;
        if (node < n) h_next[(size_t)node * STRIDE + j] = lrelu(fmaxf(acc[u], 0.f));
      }
    }
  }
}

// ---------------- layers 2/3: fused CSR gather + node update ----------------
// Wave w gathers NPW nodes (registers -> LDS), then block does the matmuls.

template <int FIN, int FOUT, int UN>
__global__ __launch_bounds__(256) void k_layer(
    const float* __restrict__ h_prev, float* __restrict__ h_next,
    const int* __restrict__ rend, const int* __restrict__ csr_row,
    const float* __restrict__ csr_w,
    const float* __restrict__ gw, const float* __restrict__ gb,
    const float* __restrict__ w1, const float* __restrict__ b1,
    const float* __restrict__ w2, const float* __restrict__ b2,
    const float* __restrict__ epsp, int n) {
  constexpr int STRIDE = 2 * FOUT;
  constexpr int G = 256 / STRIDE;
  constexpr int NPB = G * UN;
  constexpr int NPW = (NPB + 3) / 4;  // nodes gathered per wave
  __shared__ float W[FIN * FOUT];
  __shared__ float W1s[FIN * 10];
  __shared__ float W2s[10 * FOUT];
  __shared__ float GB[FOUT];
  __shared__ float B1[10];
  __shared__ float B2[FOUT];
  __shared__ float AGG[NPB][FIN];
  __shared__ float M[NPB][FIN + 2];
  __shared__ float T[NPB][10];
  const int tid = threadIdx.x;
  for (int i = tid; i < FIN * FOUT; i += 256) W[i] = gw[i];
  for (int i = tid; i < FIN * 10; i += 256) W1s[i] = w1[i];
  for (int i = tid; i < 10 * FOUT; i += 256) W2s[i] = w2[i];
  for (int i = tid; i < FOUT; i += 256) { GB[i] = gb[i]; B2[i] = b2[i]; }
  if (tid < 10) B1[tid] = b1[tid];
  const float eps1 = 1.0f + epsp[0];
  const int w = tid >> 6, lane = tid & 63;
  const int g = tid / STRIDE, j = tid % STRIDE;
  for (int base = blockIdx.x * NPB; base < n; base += gridDim.x * NPB) {
    __syncthreads();
    // gather phase
    #pragma unroll
    for (int q = 0; q < NPW; ++q) {
      int nd = w * NPW + q;
      int node = base + nd;
      if (node < n) {
        int s = (node == 0) ? 0 : rend[node - 1];
        int e = rend[node];
        if constexpr (FIN == 128) {
          const float2* hp = (const float2*)h_prev;
          float a0 = 0, a1 = 0, b0 = 0, b1 = 0;
          for (int p = s; p < e; ++p) {
            int r = csr_row[p];
            float wgt = csr_w[p];
            float2 v = hp[(size_t)r * 64 + lane];
            a0 += v.x * wgt; a1 += v.y * wgt; b0 += v.x; b1 += v.y;
          }
          float2 hm = ((const float2*)h_prev)[(size_t)node * 64 + lane];
          AGG[nd][2 * lane] = a0; AGG[nd][2 * lane + 1] = a1;
          M[nd][2 * lane] = eps1 * hm.x + b0;
          M[nd][2 * lane + 1] = eps1 * hm.y + b1;
        } else {
          float a0 = 0, b0 = 0;
          for (int p = s; p < e; ++p) {
            int r = csr_row[p];
            float wgt = csr_w[p];
            float v = h_prev[(size_t)r * FIN + lane];
            a0 += v * wgt; b0 += v;
          }
          AGG[nd][lane] = a0;
          M[nd][lane] = eps1 * h_prev[(size_t)node * FIN + lane] + b0;
        }
      }
    }
    __syncthreads();
    // GIN hidden layer
    if (tid < NPB * 16) {
      int nd = tid >> 4, k = tid & 15;
      if (k < 10 && base + nd < n) {
        float acc = B1[k];
        #pragma unroll 4
        for (int f = 0; f < FIN; ++f) acc += M[nd][f] * W1s[f * 10 + k];
        T[nd][k] = fmaxf(acc, 0.f);
      }
    }
    __syncthreads();
    // output matmuls
    float acc[UN];
    const int nd0 = g * UN;
    if (j < FOUT) {
      #pragma unroll
      for (int u = 0; u < UN; ++u) acc[u] = GB[j];
      for (int f = 0; f < FIN; ++f) {
        float wv = W[f * FOUT + j];
        #pragma unroll
        for (int u = 0; u < UN; ++u) acc[u] += AGG[nd0 + u][f] * wv;
      }
      #pragma unroll
      for (int u = 0; u < UN; ++u) {
        int node = base + nd0 + u;
        if (node < n) h_next[(size_t)node * STRIDE + j] = lrelu(acc[u]);
      }
    } else {
      int jj = j - FOUT;
      #pragma unroll
      for (int u = 0; u < UN; ++u) acc[u] = B2[jj];
      #pragma unroll
      for (int k = 0; k < 10; ++k) {
        float wv = W2s[k * FOUT + jj];
        #pragma unroll
        for (int u = 0; u < UN; ++u) acc[u] += T[nd0 + u][k] * wv;
      }
      #pragma unroll
      for (int u = 0; u < UN; ++u) {
        int node = base + nd0 + u;
        if (node < n) h_next[(size_t)node * STRIDE + j] = lrelu(fmaxf(acc[u], 0.f));
      }
    }
  }
}

// ---------------- GAT + pool ----------------

__global__ __launch_bounds__(256) void k_hj(const float* __restrict__ h3,
                                            const float* __restrict__ gw,
                                            float* __restrict__ hj, int n) {
  int wid = blockIdx.x * 4 + (threadIdx.x >> 6);
  int lane = threadIdx.x & 63;
  if (wid >= n) return;
  const float* r = h3 + (size_t)wid * 256;
  float acc = r[lane] * gw[lane] + r[lane + 64] * gw[lane + 64] +
              r[lane + 128] * gw[lane + 128] + r[lane + 192] * gw[lane + 192];
  for (int o = 32; o > 0; o >>= 1) acc += __shfl_down(acc, o);
  if (lane == 0) hj[wid] = acc;
}

__global__ void k_edge_max(const int* __restrict__ row, const float* __restrict__ hj,
                           const float* __restrict__ att, float* __restrict__ red, int ne) {
  float a = att[0];
  float m = -INFINITY;
  for (int e = blockIdx.x * blockDim.x + threadIdx.x; e < ne; e += gridDim.x * blockDim.x) {
    m = fmaxf(m, lrelu(a * hj[row[e]]));
  }
  for (int o = 32; o > 0; o >>= 1) m = fmaxf(m, __shfl_down(m, o));
  if ((threadIdx.x & 63) == 0) atomicMaxF(&red[6], m);
}

// per-node gather: unnormalized att_weight and global sumexp
__global__ void k_gat(const int* __restrict__ rend, const int* __restrict__ csr_row,
                      const float* __restrict__ hj, const float* __restrict__ att,
                      float* __restrict__ red, float* __restrict__ scat, int n) {
  int c = blockIdx.x * 256 + threadIdx.x;
  float a = att[0];
  float m = red[6];
  float lsum = 0.f;
  if (c < n) {
    int s = (c == 0) ? 0 : rend[c - 1];
    int e = rend[c];
    float acc = 0.f;
    for (int p = s; p < e; ++p) {
      float h = hj[csr_row[p]];
      float pex = expf(lrelu(a * h) - m);
      lsum += pex;
      acc += pex * h;
    }
    scat[c] = acc;
  }
  for (int o = 32; o > 0; o >>= 1) lsum += __shfl_down(lsum, o);
  if ((threadIdx.x & 63) == 0) atomicAdd(&red[7], lsum);
}

__global__ __launch_bounds__(256) void k_pool(
    const float* __restrict__ h3, const float* __restrict__ scat, const float* __restrict__ red,
    const float* __restrict__ lw, const float* __restrict__ lb,
    const float* __restrict__ l2w, const float* __restrict__ l2b,
    float* __restrict__ out, int ng) {
  __shared__ float pooled[256];
  __shared__ float aw[NPGC];
  __shared__ float y[10];
  int g = blockIdx.x;
  if (g >= ng) return;
  int tid = threadIdx.x;
  float inv_sexp = 1.0f / red[7];
  if (tid < NPGC) aw[tid] = scat[g * NPGC + tid] * inv_sexp;
  __syncthreads();
  const float* base = h3 + (size_t)g * NPGC * 256;
  float acc = 0.f;
  #pragma unroll
  for (int u = 0; u < NPGC; ++u) acc += base[u * 256 + tid] * aw[u];
  pooled[tid] = acc * (1.0f / NPGC);
  __syncthreads();
  if (tid < 10) {
    float s = lb[tid];
    for (int f = 0; f < 256; ++f) s += pooled[f] * lw[f * 10 + tid];
    y[tid] = s;
  }
  __syncthreads();
  if (tid == 0) {
    float s = l2b[0];
    #pragma unroll
    for (int k = 0; k < 10; ++k) s += y[k] * l2w[k];
    out[g] = 1.0f / (1.0f + expf(-s));
  }
}

extern "C" void kernel_launch(void* const* d_in, const int* in_sizes, int n_in,
                              void* d_out, int out_size, void* d_ws, size_t ws_size,
                              hipStream_t stream) {
  const float* x        = (const float*)d_in[0];
  const int*   eidx     = (const int*)d_in[1];
  const float* ew       = (const float*)d_in[2];
  const float* gcn1_w   = (const float*)d_in[3];
  const float* gcn1_b   = (const float*)d_in[4];
  const float* gcn2_w   = (const float*)d_in[5];
  const float* gcn2_b   = (const float*)d_in[6];
  const float* gcn3_w   = (const float*)d_in[7];
  const float* gcn3_b   = (const float*)d_in[8];
  const float* gin1_w1  = (const float*)d_in[9];
  const float* gin1_b1  = (const float*)d_in[10];
  const float* gin1_w2  = (const float*)d_in[11];
  const float* gin1_b2  = (const float*)d_in[12];
  const float* gin1_eps = (const float*)d_in[13];
  const float* gin2_w1  = (const float*)d_in[14];
  const float* gin2_b1  = (const float*)d_in[15];
  const float* gin2_w2  = (const float*)d_in[16];
  const float* gin2_b2  = (const float*)d_in[17];
  const float* gin2_eps = (const float*)d_in[18];
  const float* gin3_w1  = (const float*)d_in[19];
  const float* gin3_b1  = (const float*)d_in[20];
  const float* gin3_w2  = (const float*)d_in[21];
  const float* gin3_b2  = (const float*)d_in[22];
  const float* gin3_eps = (const float*)d_in[23];
  const float* gat_w    = (const float*)d_in[24];
  const float* gat_att  = (const float*)d_in[25];
  const float* lin_w    = (const float*)d_in[26];
  const float* lin_b    = (const float*)d_in[27];
  const float* lin2_w   = (const float*)d_in[28];
  const float* lin2_b   = (const float*)d_in[29];
  float* out = (float*)d_out;

  const int* row = eidx;
  const int* col = eidx + N_EDGES;

  // Workspace layout (peak ≈ 240.6 MB):
  //  P3 [N*256 f32]: scratch(deg/bsum) -> h1 (N*64, layers 1-2) -> h3 (layer 3 .. pool)
  //  P2 [N*128 f32]: x0 (N*3, layer 1) -> h2 (layer 2-3) -> hj [0:N] + scat [N:2N]
  //  persistent: rowptr[N] (post-fill = segment ends), csr_row[E], csr_w[E], red[64]
  float* ws      = (float*)d_ws;
  float* P3      = ws;                           // N*256 floats
  float* P2      = ws + (size_t)N_NODES * 256;   // N*128 floats
  int*   rowptr  = (int*)(ws + (size_t)N_NODES * 384);
  int*   csr_row = rowptr + N_NODES;
  float* csr_w   = (float*)(csr_row + N_EDGES);
  float* red     = csr_w + N_EDGES;

  int* deg  = (int*)P3;          // dead after scan1
  int* bsum = deg + N_NODES;     // dead after scan3

  float* x0   = P2;              // dies after k_node (layer 1)
  float* h1   = P3;              // dies after k_layer (layer 2)
  float* h2   = P2;              // dies after k_layer (layer 3)
  float* h3   = P3;              // lives to the end
  float* hj   = P2;              // born after layer 3
  float* scat = P2 + N_NODES;

  const int GE = (N_EDGES + 255) / 256;
  const int GN = (N_NODES + 255) / 256;

  // CSR build
  hipMemsetAsync(deg, 0, (size_t)N_NODES * 4, stream);
  hipLaunchKernelGGL(k_degree, dim3(GE), dim3(256), 0, stream, col, deg, N_EDGES);
  hipLaunchKernelGGL(k_scan1, dim3(NB_SCAN), dim3(256), 0, stream, deg, rowptr, bsum, N_NODES);
  hipLaunchKernelGGL(k_scan2, dim3(1), dim3(256), 0, stream, bsum, NB_SCAN);
  hipLaunchKernelGGL(k_scan3, dim3(GN), dim3(256), 0, stream, rowptr, bsum, N_NODES);
  hipLaunchKernelGGL(k_fill, dim3(GE), dim3(256), 0, stream, row, col, ew, rowptr, csr_row, csr_w, N_EDGES);

  // normalization
  hipLaunchKernelGGL(k_init, dim3(1), dim3(64), 0, stream, red);
  hipLaunchKernelGGL(k_colstats, dim3(256), dim3(256), 0, stream, x, red, N_NODES);
  hipLaunchKernelGGL(k_norm, dim3((N_NODES * 3 + 255) / 256), dim3(256), 0, stream, x, red, x0, N_NODES);

  // layer 1: 3 -> 32|32 (gather into h1 agg slots, then in-place node update)
  hipLaunchKernelGGL(k_gather3, dim3(GN), dim3(256), 0, stream, x0, rowptr, csr_row, csr_w, h1, N_NODES);
  hipLaunchKernelGGL((k_node<3, 32, 4>), dim3(512), dim3(256), 0, stream,
                     x0, h1, gcn1_w, gcn1_b, gin1_w1, gin1_b1, gin1_w2, gin1_b2, gin1_eps, N_NODES);

  // layer 2: 64 -> 64|64 (fused gather + update), h1 -> h2
  hipLaunchKernelGGL((k_layer<64, 64, 4>), dim3(2048), dim3(256), 0, stream,
                     h1, h2, rowptr, csr_row, csr_w,
                     gcn2_w, gcn2_b, gin2_w1, gin2_b1, gin2_w2, gin2_b2, gin2_eps, N_NODES);

  // layer 3: 128 -> 128|128 (fused gather + update), h2 -> h3
  hipLaunchKernelGGL((k_layer<128, 128, 4>), dim3(2048), dim3(256), 0, stream,
                     h2, h3, rowptr, csr_row, csr_w,
                     gcn3_w, gcn3_b, gin3_w1, gin3_b1, gin3_w2, gin3_b2, gin3_eps, N_NODES);

  // GAT (h2 dead; hj/scat reuse P2)
  hipLaunchKernelGGL(k_hj, dim3((N_NODES + 3) / 4), dim3(256), 0, stream, h3, gat_w, hj, N_NODES);
  hipLaunchKernelGGL(k_edge_max, dim3(1024), dim3(256), 0, stream, row, hj, gat_att, red, N_EDGES);
  hipLaunchKernelGGL(k_gat, dim3(GN), dim3(256), 0, stream, rowptr, csr_row, hj, gat_att, red, scat, N_NODES);

  // pool + readout
  hipLaunchKernelGGL(k_pool, dim3(NGRAPH), dim3(256), 0, stream,
                     h3, scat, red, lin_w, lin_b, lin2_w, lin2_b, out, NGRAPH);
}

// Round 4
// 1347.039 us; speedup vs baseline: 2.1492x; 1.6235x over previous
//
#include <hip/hip_runtime.h>
#include <hip/hip_bf16.h>
#include <math.h>

constexpr int N_NODES = 150000;
constexpr int N_EDGES = 1200000;
constexpr int NPGC    = 30;
constexpr int NGRAPH  = N_NODES / NPGC;
constexpr int NB_SCAN = (N_NODES + 1023) / 1024;   // 147 scan blocks

__device__ __forceinline__ float lrelu(float v) { return v > 0.f ? v : 0.2f * v; }

__device__ float atomicMaxF(float* addr, float val) {
  int* ia = (int*)addr;
  int old = *ia;
  while (__int_as_float(old) < val) {
    int assumed = old;
    old = atomicCAS(ia, assumed, __float_as_int(val));
    if (old == assumed) break;
  }
  return __int_as_float(old);
}

// ---------------- CSR build (per launch; deterministic rebuild) ----------------

__global__ void k_degree(const int* __restrict__ col, int* __restrict__ deg, int ne) {
  int e = blockIdx.x * 256 + threadIdx.x;
  if (e < ne) atomicAdd(&deg[col[e]], 1);
}

__global__ __launch_bounds__(256) void k_scan1(const int* __restrict__ deg,
                                               int* __restrict__ rowptr,
                                               int* __restrict__ bsum, int n) {
  __shared__ int ts[256];
  int b = blockIdx.x, tid = threadIdx.x;
  int base = b * 1024 + tid * 4;
  int d[4]; int s = 0;
  #pragma unroll
  for (int k = 0; k < 4; ++k) { d[k] = (base + k < n) ? deg[base + k] : 0; s += d[k]; }
  ts[tid] = s;
  __syncthreads();
  for (int off = 1; off < 256; off <<= 1) {
    int v = (tid >= off) ? ts[tid - off] : 0;
    __syncthreads();
    ts[tid] += v;
    __syncthreads();
  }
  int run = ts[tid] - s;
  #pragma unroll
  for (int k = 0; k < 4; ++k) {
    if (base + k < n) rowptr[base + k] = run;
    run += d[k];
  }
  if (tid == 255) bsum[b] = ts[255];
}

__global__ __launch_bounds__(256) void k_scan2(int* __restrict__ bsum, int nb) {
  __shared__ int ts[256];
  int tid = threadIdx.x;
  int orig = (tid < nb) ? bsum[tid] : 0;
  ts[tid] = orig;
  __syncthreads();
  for (int off = 1; off < 256; off <<= 1) {
    int v = (tid >= off) ? ts[tid - off] : 0;
    __syncthreads();
    ts[tid] += v;
    __syncthreads();
  }
  if (tid < nb) bsum[tid] = ts[tid] - orig;
}

__global__ void k_scan3(int* __restrict__ rowptr, const int* __restrict__ bsum, int n) {
  int i = blockIdx.x * 256 + threadIdx.x;
  if (i < n) rowptr[i] += bsum[i >> 10];
}

// fill: rowptr doubles as cursor; afterwards rowptr[c] == end(c), start(c)=rowptr[c-1]
__global__ void k_fill(const int* __restrict__ row, const int* __restrict__ col,
                       const float* __restrict__ ew, int* __restrict__ rowptr,
                       int* __restrict__ csr_row, float* __restrict__ csr_w, int ne) {
  int e = blockIdx.x * 256 + threadIdx.x;
  if (e >= ne) return;
  int c = col[e];
  int p = atomicAdd(&rowptr[c], 1);
  csr_row[p] = row[e];
  csr_w[p] = ew[e];
}

// ---------------- input normalization ----------------

// red layout: [0..2] colsum, [3..5] colmax, [6] softmax max, [7] softmax sumexp
__global__ void k_init(float* red) {
  int t = threadIdx.x;
  if (t < 3) red[t] = 0.f;
  else if (t < 7) red[t] = -INFINITY;
  else if (t == 7) red[t] = 0.f;
}

__global__ void k_colstats(const float* __restrict__ x, float* __restrict__ red, int n) {
  float s0 = 0, s1 = 0, s2 = 0;
  float m0 = -INFINITY, m1 = -INFINITY, m2 = -INFINITY;
  for (int i = blockIdx.x * blockDim.x + threadIdx.x; i < n; i += gridDim.x * blockDim.x) {
    float v0 = x[3 * i], v1 = x[3 * i + 1], v2 = x[3 * i + 2];
    s0 += v0; s1 += v1; s2 += v2;
    m0 = fmaxf(m0, v0); m1 = fmaxf(m1, v1); m2 = fmaxf(m2, v2);
  }
  for (int o = 32; o > 0; o >>= 1) {
    s0 += __shfl_down(s0, o); s1 += __shfl_down(s1, o); s2 += __shfl_down(s2, o);
    m0 = fmaxf(m0, __shfl_down(m0, o));
    m1 = fmaxf(m1, __shfl_down(m1, o));
    m2 = fmaxf(m2, __shfl_down(m2, o));
  }
  if ((threadIdx.x & 63) == 0) {
    atomicAdd(&red[0], s0); atomicAdd(&red[1], s1); atomicAdd(&red[2], s2);
    atomicMaxF(&red[3], m0); atomicMaxF(&red[4], m1); atomicMaxF(&red[5], m2);
  }
}

__global__ void k_norm(const float* __restrict__ x, const float* __restrict__ red,
                       float* __restrict__ x0, int n) {
  int i = blockIdx.x * 256 + threadIdx.x;
  if (i >= n * 3) return;
  int c = i % 3;
  float mean = red[c] / (float)n;
  float denom = red[3 + c] - mean;   // max(x - mean) = max(x) - mean
  x0[i] = (x[i] - mean) / denom;
}

// ---------------- layer 1 (FIN=3): gather agg + M into h1 slots ----------------

__global__ void k_gather3(const float* __restrict__ x0, const int* __restrict__ rend,
                          const int* __restrict__ csr_row, const float* __restrict__ csr_w,
                          const float* __restrict__ epsp, float* __restrict__ h1, int n) {
  int c = blockIdx.x * 256 + threadIdx.x;
  if (c >= n) return;
  int s = (c == 0) ? 0 : rend[c - 1];
  int e = rend[c];
  float a0 = 0, a1 = 0, a2 = 0, b0 = 0, b1 = 0, b2 = 0;
  for (int p = s; p < e; ++p) {
    int r = csr_row[p];
    float w = csr_w[p];
    float v0 = x0[3 * r], v1 = x0[3 * r + 1], v2 = x0[3 * r + 2];
    a0 += v0 * w; a1 += v1 * w; a2 += v2 * w;
    b0 += v0; b1 += v1; b2 += v2;
  }
  float eps1 = 1.0f + epsp[0];
  float* ap = h1 + (size_t)c * 64;
  ap[0] = a0; ap[1] = a1; ap[2] = a2;
  ap[3] = eps1 * x0[3 * c] + b0;
  ap[4] = eps1 * x0[3 * c + 1] + b1;
  ap[5] = eps1 * x0[3 * c + 2] + b2;
}

// ---------------- edge-parallel SpMM: one wave per node ----------------
// Lanes = edge-group (EG) x feature-slot (LPF, float4 each). Writes
// AGG to h_next[node*2FIN + 0:FIN) and M = (1+eps)*h_prev + aggB to [FIN:2FIN).

template <int FIN>
__global__ __launch_bounds__(256) void k_spmm(
    const float* __restrict__ h_prev, float* __restrict__ h_next,
    const int* __restrict__ rend, const int* __restrict__ csr_row,
    const float* __restrict__ csr_w, const float* __restrict__ epsp, int n) {
  constexpr int LPF = FIN / 4;    // lanes covering one row (16 or 32)
  constexpr int EG  = 64 / LPF;   // edges in flight per wave (4 or 2)
  int wid = (blockIdx.x * 256 + threadIdx.x) >> 6;
  if (wid >= n) return;
  int lane = threadIdx.x & 63;
  int fl = lane & (LPF - 1);
  int eg = lane / LPF;
  int s = (wid == 0) ? 0 : rend[wid - 1];
  int e = rend[wid];
  const float4* hp = (const float4*)h_prev;
  float ax = 0, ay = 0, az = 0, aw = 0;
  float bx = 0, by = 0, bz = 0, bw = 0;
  for (int p = s + eg; p < e; p += EG) {
    int r = csr_row[p];
    float w = csr_w[p];
    float4 v = hp[(size_t)r * LPF + fl];
    ax += v.x * w; ay += v.y * w; az += v.z * w; aw += v.w * w;
    bx += v.x; by += v.y; bz += v.z; bw += v.w;
  }
  #pragma unroll
  for (int off = LPF; off < 64; off <<= 1) {
    ax += __shfl_xor(ax, off); ay += __shfl_xor(ay, off);
    az += __shfl_xor(az, off); aw += __shfl_xor(aw, off);
    bx += __shfl_xor(bx, off); by += __shfl_xor(by, off);
    bz += __shfl_xor(bz, off); bw += __shfl_xor(bw, off);
  }
  if (eg == 0) {
    float eps1 = 1.0f + epsp[0];
    float4 hm = hp[(size_t)wid * LPF + fl];
    float4* hn = (float4*)h_next;
    float4 a; a.x = ax; a.y = ay; a.z = az; a.w = aw;
    hn[(size_t)wid * (2 * LPF) + fl] = a;
    float4 m;
    m.x = eps1 * hm.x + bx; m.y = eps1 * hm.y + by;
    m.z = eps1 * hm.z + bz; m.w = eps1 * hm.w + bw;
    hn[(size_t)wid * (2 * LPF) + LPF + fl] = m;
  }
}

// ---------------- node update (matmul only): in place on h_next ----------------
// h_next rows (stride 2*FOUT) hold [AGG | M] in [0:2*FIN); overwritten with
// lrelu(concat(GCN, GIN)).

template <int FIN, int FOUT, int UN>
__global__ __launch_bounds__(256) void k_node(
    float* __restrict__ h_next,
    const float* __restrict__ gw, const float* __restrict__ gb,
    const float* __restrict__ w1, const float* __restrict__ b1,
    const float* __restrict__ w2, const float* __restrict__ b2, int n) {
  constexpr int STRIDE = 2 * FOUT;
  constexpr int G = 256 / STRIDE;
  constexpr int NPB = G * UN;
  __shared__ float W[FIN * FOUT];
  __shared__ float W1s[FIN * 10];
  __shared__ float W2s[10 * FOUT];
  __shared__ float GB[FOUT];
  __shared__ float B1[10];
  __shared__ float B2[FOUT];
  __shared__ float AGG[NPB][FIN];
  __shared__ float M[NPB][FIN + 2];
  __shared__ float T[NPB][10];
  const int tid = threadIdx.x;
  for (int i = tid; i < FIN * FOUT; i += 256) W[i] = gw[i];
  for (int i = tid; i < FIN * 10; i += 256) W1s[i] = w1[i];
  for (int i = tid; i < 10 * FOUT; i += 256) W2s[i] = w2[i];
  for (int i = tid; i < FOUT; i += 256) { GB[i] = gb[i]; B2[i] = b2[i]; }
  if (tid < 10) B1[tid] = b1[tid];
  const int g = tid / STRIDE;
  const int j = tid % STRIDE;
  for (int base = blockIdx.x * NPB; base < n; base += gridDim.x * NPB) {
    __syncthreads();
    for (int i = tid; i < NPB * FIN; i += 256) {
      int nd = i / FIN, f = i % FIN;
      int node = base + nd;
      if (node < n) {
        AGG[nd][f] = h_next[(size_t)node * STRIDE + f];
        M[nd][f] = h_next[(size_t)node * STRIDE + FIN + f];
      }
    }
    __syncthreads();
    if (tid < NPB * 16) {
      int nd = tid >> 4, k = tid & 15;
      if (k < 10 && base + nd < n) {
        float acc = B1[k];
        #pragma unroll 4
        for (int f = 0; f < FIN; ++f) acc += M[nd][f] * W1s[f * 10 + k];
        T[nd][k] = fmaxf(acc, 0.f);
      }
    }
    __syncthreads();
    float acc[UN];
    const int nd0 = g * UN;
    if (j < FOUT) {
      #pragma unroll
      for (int u = 0; u < UN; ++u) acc[u] = GB[j];
      for (int f = 0; f < FIN; ++f) {
        float wv = W[f * FOUT + j];
        #pragma unroll
        for (int u = 0; u < UN; ++u) acc[u] += AGG[nd0 + u][f] * wv;
      }
      #pragma unroll
      for (int u = 0; u < UN; ++u) {
        int node = base + nd0 + u;
        if (node < n) h_next[(size_t)node * STRIDE + j] = lrelu(acc[u]);
      }
    } else {
      int jj = j - FOUT;
      #pragma unroll
      for (int u = 0; u < UN; ++u) acc[u] = B2[jj];
      #pragma unroll
      for (int k = 0; k < 10; ++k) {
        float wv = W2s[k * FOUT + jj];
        #pragma unroll
        for (int u = 0; u < UN; ++u) acc[u] += T[nd0 + u][k] * wv;
      }
      #pragma unroll
      for (int u = 0; u < UN; ++u) {
        int node = base + nd0 + u;
        if (node < n) h_next[(size_t)node * STRIDE + j] = lrelu(fmaxf(acc[u], 0.f));
      }
    }
  }
}

// ---------------- GAT + pool ----------------

__global__ __launch_bounds__(256) void k_hj(const float* __restrict__ h3,
                                            const float* __restrict__ gw,
                                            float* __restrict__ hj, int n) {
  int wid = blockIdx.x * 4 + (threadIdx.x >> 6);
  int lane = threadIdx.x & 63;
  if (wid >= n) return;
  const float* r = h3 + (size_t)wid * 256;
  float acc = r[lane] * gw[lane] + r[lane + 64] * gw[lane + 64] +
              r[lane + 128] * gw[lane + 128] + r[lane + 192] * gw[lane + 192];
  for (int o = 32; o > 0; o >>= 1) acc += __shfl_down(acc, o);
  if (lane == 0) hj[wid] = acc;
}

__global__ void k_edge_max(const int* __restrict__ row, const float* __restrict__ hj,
                           const float* __restrict__ att, float* __restrict__ red, int ne) {
  float a = att[0];
  float m = -INFINITY;
  for (int e = blockIdx.x * blockDim.x + threadIdx.x; e < ne; e += gridDim.x * blockDim.x) {
    m = fmaxf(m, lrelu(a * hj[row[e]]));
  }
  for (int o = 32; o > 0; o >>= 1) m = fmaxf(m, __shfl_down(m, o));
  if ((threadIdx.x & 63) == 0) atomicMaxF(&red[6], m);
}

__global__ void k_gat(const int* __restrict__ rend, const int* __restrict__ csr_row,
                      const float* __restrict__ hj, const float* __restrict__ att,
                      float* __restrict__ red, float* __restrict__ scat, int n) {
  int c = blockIdx.x * 256 + threadIdx.x;
  float a = att[0];
  float m = red[6];
  float lsum = 0.f;
  if (c < n) {
    int s = (c == 0) ? 0 : rend[c - 1];
    int e = rend[c];
    float acc = 0.f;
    for (int p = s; p < e; ++p) {
      float h = hj[csr_row[p]];
      float pex = expf(lrelu(a * h) - m);
      lsum += pex;
      acc += pex * h;
    }
    scat[c] = acc;
  }
  for (int o = 32; o > 0; o >>= 1) lsum += __shfl_down(lsum, o);
  if ((threadIdx.x & 63) == 0) atomicAdd(&red[7], lsum);
}

__global__ __launch_bounds__(256) void k_pool(
    const float* __restrict__ h3, const float* __restrict__ scat, const float* __restrict__ red,
    const float* __restrict__ lw, const float* __restrict__ lb,
    const float* __restrict__ l2w, const float* __restrict__ l2b,
    float* __restrict__ out, int ng) {
  __shared__ float pooled[256];
  __shared__ float aw[NPGC];
  __shared__ float y[10];
  int g = blockIdx.x;
  if (g >= ng) return;
  int tid = threadIdx.x;
  float inv_sexp = 1.0f / red[7];
  if (tid < NPGC) aw[tid] = scat[g * NPGC + tid] * inv_sexp;
  __syncthreads();
  const float* base = h3 + (size_t)g * NPGC * 256;
  float acc = 0.f;
  #pragma unroll
  for (int u = 0; u < NPGC; ++u) acc += base[u * 256 + tid] * aw[u];
  pooled[tid] = acc * (1.0f / NPGC);
  __syncthreads();
  if (tid < 10) {
    float s = lb[tid];
    for (int f = 0; f < 256; ++f) s += pooled[f] * lw[f * 10 + tid];
    y[tid] = s;
  }
  __syncthreads();
  if (tid == 0) {
    float s = l2b[0];
    #pragma unroll
    for (int k = 0; k < 10; ++k) s += y[k] * l2w[k];
    out[g] = 1.0f / (1.0f + expf(-s));
  }
}

extern "C" void kernel_launch(void* const* d_in, const int* in_sizes, int n_in,
                              void* d_out, int out_size, void* d_ws, size_t ws_size,
                              hipStream_t stream) {
  const float* x        = (const float*)d_in[0];
  const int*   eidx     = (const int*)d_in[1];
  const float* ew       = (const float*)d_in[2];
  const float* gcn1_w   = (const float*)d_in[3];
  const float* gcn1_b   = (const float*)d_in[4];
  const float* gcn2_w   = (const float*)d_in[5];
  const float* gcn2_b   = (const float*)d_in[6];
  const float* gcn3_w   = (const float*)d_in[7];
  const float* gcn3_b   = (const float*)d_in[8];
  const float* gin1_w1  = (const float*)d_in[9];
  const float* gin1_b1  = (const float*)d_in[10];
  const float* gin1_w2  = (const float*)d_in[11];
  const float* gin1_b2  = (const float*)d_in[12];
  const float* gin1_eps = (const float*)d_in[13];
  const float* gin2_w1  = (const float*)d_in[14];
  const float* gin2_b1  = (const float*)d_in[15];
  const float* gin2_w2  = (const float*)d_in[16];
  const float* gin2_b2  = (const float*)d_in[17];
  const float* gin2_eps = (const float*)d_in[18];
  const float* gin3_w1  = (const float*)d_in[19];
  const float* gin3_b1  = (const float*)d_in[20];
  const float* gin3_w2  = (const float*)d_in[21];
  const float* gin3_b2  = (const float*)d_in[22];
  const float* gin3_eps = (const float*)d_in[23];
  const float* gat_w    = (const float*)d_in[24];
  const float* gat_att  = (const float*)d_in[25];
  const float* lin_w    = (const float*)d_in[26];
  const float* lin_b    = (const float*)d_in[27];
  const float* lin2_w   = (const float*)d_in[28];
  const float* lin2_b   = (const float*)d_in[29];
  float* out = (float*)d_out;

  const int* row = eidx;
  const int* col = eidx + N_EDGES;

  // Workspace layout (peak ≈ 240.6 MB):
  //  P3 [N*256 f32]: scratch(deg/bsum) -> h1 (N*64, layers 1-2) -> h3 (layer 3 .. pool)
  //  P2 [N*128 f32]: x0 (N*3, layer 1) -> h2 (layer 2-3) -> hj [0:N] + scat [N:2N]
  //  persistent: rowptr[N] (post-fill = segment ends), csr_row[E], csr_w[E], red[64]
  float* ws      = (float*)d_ws;
  float* P3      = ws;                           // N*256 floats
  float* P2      = ws + (size_t)N_NODES * 256;   // N*128 floats
  int*   rowptr  = (int*)(ws + (size_t)N_NODES * 384);
  int*   csr_row = rowptr + N_NODES;
  float* csr_w   = (float*)(csr_row + N_EDGES);
  float* red     = csr_w + N_EDGES;

  int* deg  = (int*)P3;          // dead after scan1
  int* bsum = deg + N_NODES;     // dead after scan3

  float* x0   = P2;              // dies after k_spmm (layer 2)
  float* h1   = P3;              // dies after k_spmm (layer 3)... (layer-2 spmm reads it)
  float* h2   = P2;              // dies after k_spmm (layer 3)
  float* h3   = P3;              // lives to the end
  float* hj   = P2;              // born after layer 3
  float* scat = P2 + N_NODES;

  const int GE = (N_EDGES + 255) / 256;
  const int GN = (N_NODES + 255) / 256;
  const int GW = (N_NODES + 3) / 4;   // one wave per node, 4 waves/block

  // CSR build
  hipMemsetAsync(deg, 0, (size_t)N_NODES * 4, stream);
  hipLaunchKernelGGL(k_degree, dim3(GE), dim3(256), 0, stream, col, deg, N_EDGES);
  hipLaunchKernelGGL(k_scan1, dim3(NB_SCAN), dim3(256), 0, stream, deg, rowptr, bsum, N_NODES);
  hipLaunchKernelGGL(k_scan2, dim3(1), dim3(256), 0, stream, bsum, NB_SCAN);
  hipLaunchKernelGGL(k_scan3, dim3(GN), dim3(256), 0, stream, rowptr, bsum, N_NODES);
  hipLaunchKernelGGL(k_fill, dim3(GE), dim3(256), 0, stream, row, col, ew, rowptr, csr_row, csr_w, N_EDGES);

  // normalization
  hipLaunchKernelGGL(k_init, dim3(1), dim3(64), 0, stream, red);
  hipLaunchKernelGGL(k_colstats, dim3(256), dim3(256), 0, stream, x, red, N_NODES);
  hipLaunchKernelGGL(k_norm, dim3((N_NODES * 3 + 255) / 256), dim3(256), 0, stream, x, red, x0, N_NODES);

  // layer 1: 3 -> 32|32
  hipLaunchKernelGGL(k_gather3, dim3(GN), dim3(256), 0, stream,
                     x0, rowptr, csr_row, csr_w, gin1_eps, h1, N_NODES);
  hipLaunchKernelGGL((k_node<3, 32, 4>), dim3(2048), dim3(256), 0, stream,
                     h1, gcn1_w, gcn1_b, gin1_w1, gin1_b1, gin1_w2, gin1_b2, N_NODES);

  // layer 2: 64 -> 64|64 (edge-parallel SpMM h1 -> h2, then matmul on h2)
  hipLaunchKernelGGL((k_spmm<64>), dim3(GW), dim3(256), 0, stream,
                     h1, h2, rowptr, csr_row, csr_w, gin2_eps, N_NODES);
  hipLaunchKernelGGL((k_node<64, 64, 4>), dim3(2048), dim3(256), 0, stream,
                     h2, gcn2_w, gcn2_b, gin2_w1, gin2_b1, gin2_w2, gin2_b2, N_NODES);

  // layer 3: 128 -> 128|128 (SpMM h2 -> h3, then matmul on h3)
  hipLaunchKernelGGL((k_spmm<128>), dim3(GW), dim3(256), 0, stream,
                     h2, h3, rowptr, csr_row, csr_w, gin3_eps, N_NODES);
  hipLaunchKernelGGL((k_node<128, 128, 4>), dim3(2048), dim3(256), 0, stream,
                     h3, gcn3_w, gcn3_b, gin3_w1, gin3_b1, gin3_w2, gin3_b2, N_NODES);

  // GAT (h2 dead; hj/scat reuse P2)
  hipLaunchKernelGGL(k_hj, dim3((N_NODES + 3) / 4), dim3(256), 0, stream, h3, gat_w, hj, N_NODES);
  hipLaunchKernelGGL(k_edge_max, dim3(1024), dim3(256), 0, stream, row, hj, gat_att, red, N_EDGES);
  hipLaunchKernelGGL(k_gat, dim3(GN), dim3(256), 0, stream, rowptr, csr_row, hj, gat_att, red, scat, N_NODES);

  // pool + readout
  hipLaunchKernelGGL(k_pool, dim3(NGRAPH), dim3(256), 0, stream,
                     h3, scat, red, lin_w, lin_b, lin2_w, lin2_b, out, NGRAPH);
}

// Round 5
// 630.864 us; speedup vs baseline: 4.5889x; 2.1352x over previous
//
#include <hip/hip_runtime.h>
#include <hip/hip_bf16.h>
#include <math.h>

constexpr int N_NODES = 150000;
constexpr int N_EDGES = 1200000;
constexpr int NPGC    = 30;
constexpr int NGRAPH  = N_NODES / NPGC;
constexpr int NB_SCAN = (N_NODES + 1023) / 1024;

typedef unsigned int u32;
typedef unsigned short u16;
typedef __attribute__((ext_vector_type(8))) short bf16x8;
typedef __attribute__((ext_vector_type(4))) float f32x4;

__device__ __forceinline__ float lrelu(float v) { return v > 0.f ? v : 0.2f * v; }
__device__ __forceinline__ float bf2f(u32 h) { return __uint_as_float(h << 16); }
__device__ __forceinline__ u16 f2bf(float f) {
  u32 u = __float_as_uint(f);
  return (u16)((u + 0x7FFFu + ((u >> 16) & 1u)) >> 16);
}
__device__ __forceinline__ void unpack8(uint4 v, float* f) {
  f[0] = bf2f(v.x & 0xffff); f[1] = bf2f(v.x >> 16);
  f[2] = bf2f(v.y & 0xffff); f[3] = bf2f(v.y >> 16);
  f[4] = bf2f(v.z & 0xffff); f[5] = bf2f(v.z >> 16);
  f[6] = bf2f(v.w & 0xffff); f[7] = bf2f(v.w >> 16);
}

__device__ float atomicMaxF(float* addr, float val) {
  int* ia = (int*)addr;
  int old = *ia;
  while (__int_as_float(old) < val) {
    int assumed = old;
    old = atomicCAS(ia, assumed, __float_as_int(val));
    if (old == assumed) break;
  }
  return __int_as_float(old);
}

// ---------------- CSR build ----------------

__global__ void k_degree(const int* __restrict__ col, int* __restrict__ deg, int ne) {
  int e = blockIdx.x * 256 + threadIdx.x;
  if (e < ne) atomicAdd(&deg[col[e]], 1);
}

__global__ __launch_bounds__(256) void k_scan1(const int* __restrict__ deg,
                                               int* __restrict__ rowptr,
                                               int* __restrict__ bsum, int n) {
  __shared__ int ts[256];
  int b = blockIdx.x, tid = threadIdx.x;
  int base = b * 1024 + tid * 4;
  int d[4]; int s = 0;
  #pragma unroll
  for (int k = 0; k < 4; ++k) { d[k] = (base + k < n) ? deg[base + k] : 0; s += d[k]; }
  ts[tid] = s;
  __syncthreads();
  for (int off = 1; off < 256; off <<= 1) {
    int v = (tid >= off) ? ts[tid - off] : 0;
    __syncthreads();
    ts[tid] += v;
    __syncthreads();
  }
  int run = ts[tid] - s;
  #pragma unroll
  for (int k = 0; k < 4; ++k) {
    if (base + k < n) rowptr[base + k] = run;
    run += d[k];
  }
  if (tid == 255) bsum[b] = ts[255];
}

__global__ __launch_bounds__(256) void k_scan2(int* __restrict__ bsum, int nb) {
  __shared__ int ts[256];
  int tid = threadIdx.x;
  int orig = (tid < nb) ? bsum[tid] : 0;
  ts[tid] = orig;
  __syncthreads();
  for (int off = 1; off < 256; off <<= 1) {
    int v = (tid >= off) ? ts[tid - off] : 0;
    __syncthreads();
    ts[tid] += v;
    __syncthreads();
  }
  if (tid < nb) bsum[tid] = ts[tid] - orig;
}

__global__ void k_scan3(int* __restrict__ rowptr, const int* __restrict__ bsum, int n) {
  int i = blockIdx.x * 256 + threadIdx.x;
  if (i < n) rowptr[i] += bsum[i >> 10];
}

__global__ void k_fill(const int* __restrict__ row, const int* __restrict__ col,
                       const float* __restrict__ ew, int* __restrict__ rowptr,
                       int* __restrict__ csr_row, float* __restrict__ csr_w, int ne) {
  int e = blockIdx.x * 256 + threadIdx.x;
  if (e >= ne) return;
  int c = col[e];
  int p = atomicAdd(&rowptr[c], 1);
  csr_row[p] = row[e];
  csr_w[p] = ew[e];
}

// ---------------- normalization ----------------

__global__ void k_init(float* red) {
  int t = threadIdx.x;
  if (t < 3) red[t] = 0.f;
  else if (t < 7) red[t] = -INFINITY;
  else if (t == 7) red[t] = 0.f;
}

__global__ void k_colstats(const float* __restrict__ x, float* __restrict__ red, int n) {
  float s0 = 0, s1 = 0, s2 = 0;
  float m0 = -INFINITY, m1 = -INFINITY, m2 = -INFINITY;
  for (int i = blockIdx.x * blockDim.x + threadIdx.x; i < n; i += gridDim.x * blockDim.x) {
    float v0 = x[3 * i], v1 = x[3 * i + 1], v2 = x[3 * i + 2];
    s0 += v0; s1 += v1; s2 += v2;
    m0 = fmaxf(m0, v0); m1 = fmaxf(m1, v1); m2 = fmaxf(m2, v2);
  }
  for (int o = 32; o > 0; o >>= 1) {
    s0 += __shfl_down(s0, o); s1 += __shfl_down(s1, o); s2 += __shfl_down(s2, o);
    m0 = fmaxf(m0, __shfl_down(m0, o));
    m1 = fmaxf(m1, __shfl_down(m1, o));
    m2 = fmaxf(m2, __shfl_down(m2, o));
  }
  if ((threadIdx.x & 63) == 0) {
    atomicAdd(&red[0], s0); atomicAdd(&red[1], s1); atomicAdd(&red[2], s2);
    atomicMaxF(&red[3], m0); atomicMaxF(&red[4], m1); atomicMaxF(&red[5], m2);
  }
}

__global__ void k_norm(const float* __restrict__ x, const float* __restrict__ red,
                       float* __restrict__ x0, int n) {
  int i = blockIdx.x * 256 + threadIdx.x;
  if (i >= n * 3) return;
  int c = i % 3;
  float mean = red[c] / (float)n;
  float denom = red[3 + c] - mean;
  x0[i] = (x[i] - mean) / denom;
}

// ---------------- layer 1 ----------------

__global__ void k_gather3(const float* __restrict__ x0, const int* __restrict__ rend,
                          const int* __restrict__ csr_row, const float* __restrict__ csr_w,
                          const float* __restrict__ epsp, float* __restrict__ agg1, int n) {
  int c = blockIdx.x * 256 + threadIdx.x;
  if (c >= n) return;
  int s = (c == 0) ? 0 : rend[c - 1];
  int e = rend[c];
  float a0 = 0, a1 = 0, a2 = 0, b0 = 0, b1 = 0, b2 = 0;
  for (int p = s; p < e; ++p) {
    int r = csr_row[p];
    float w = csr_w[p];
    float v0 = x0[3 * r], v1 = x0[3 * r + 1], v2 = x0[3 * r + 2];
    a0 += v0 * w; a1 += v1 * w; a2 += v2 * w;
    b0 += v0; b1 += v1; b2 += v2;
  }
  float eps1 = 1.0f + epsp[0];
  float* ap = agg1 + (size_t)c * 8;
  ap[0] = a0; ap[1] = a1; ap[2] = a2;
  ap[3] = eps1 * x0[3 * c] + b0;
  ap[4] = eps1 * x0[3 * c + 1] + b1;
  ap[5] = eps1 * x0[3 * c + 2] + b2;
}

// thread-per-node layer-1 update: 3 -> 32|32, writes bf16 h1
__global__ __launch_bounds__(256) void k_node1(
    const float* __restrict__ agg1, u16* __restrict__ h1,
    const float* __restrict__ gw, const float* __restrict__ gb,
    const float* __restrict__ w1, const float* __restrict__ b1,
    const float* __restrict__ w2, const float* __restrict__ b2, int n) {
  __shared__ float Ws[96], W1s[30], W2s[320], GBs[32], B1s[10], B2s[32];
  int tid = threadIdx.x;
  if (tid < 96) Ws[tid] = gw[tid];
  if (tid < 30) W1s[tid] = w1[tid];
  for (int i = tid; i < 320; i += 256) W2s[i] = w2[i];
  if (tid < 32) { GBs[tid] = gb[tid]; B2s[tid] = b2[tid]; }
  if (tid < 10) B1s[tid] = b1[tid];
  __syncthreads();
  int nd = blockIdx.x * 256 + tid;
  if (nd >= n) return;
  const float* a = agg1 + (size_t)nd * 8;
  float a0 = a[0], a1 = a[1], a2 = a[2], m0 = a[3], m1 = a[4], m2 = a[5];
  float t[10];
  #pragma unroll
  for (int h = 0; h < 10; ++h)
    t[h] = fmaxf(B1s[h] + m0 * W1s[h] + m1 * W1s[10 + h] + m2 * W1s[20 + h], 0.f);
  u32 w_[32];
  #pragma unroll
  for (int j = 0; j < 32; ++j) {
    float v = lrelu(GBs[j] + a0 * Ws[j] + a1 * Ws[32 + j] + a2 * Ws[64 + j]);
    u32 bv = f2bf(v);
    if (j & 1) w_[j >> 1] |= bv << 16; else w_[j >> 1] = bv;
  }
  #pragma unroll
  for (int j = 0; j < 32; ++j) {
    float s = B2s[j];
    #pragma unroll
    for (int h = 0; h < 10; ++h) s += t[h] * W2s[h * 32 + j];
    u32 bv = f2bf(fmaxf(s, 0.f));
    int jj = 32 + j;
    if (jj & 1) w_[jj >> 1] |= bv << 16; else w_[jj >> 1] = bv;
  }
  uint4* dst = (uint4*)(h1 + (size_t)nd * 64);
  #pragma unroll
  for (int q = 0; q < 8; ++q) {
    uint4 v; v.x = w_[q * 4]; v.y = w_[q * 4 + 1]; v.z = w_[q * 4 + 2]; v.w = w_[q * 4 + 3];
    dst[q] = v;
  }
}

// ---------------- bf16 edge-parallel SpMM: one wave per node ----------------

template <int FIN>
__global__ __launch_bounds__(256) void k_spmmb(
    const u16* __restrict__ hp, u16* __restrict__ Aout,
    const int* __restrict__ rend, const int* __restrict__ csr_row,
    const float* __restrict__ csr_w, const float* __restrict__ epsp, int n) {
  constexpr int LPF = FIN / 8;   // lanes per row (uint4 = 8 bf16)
  constexpr int EG  = 64 / LPF;  // edges in flight
  int wid = (blockIdx.x * 256 + threadIdx.x) >> 6;
  if (wid >= n) return;
  int lane = threadIdx.x & 63;
  int fl = lane & (LPF - 1);
  int eg = lane / LPF;
  int s = (wid == 0) ? 0 : rend[wid - 1];
  int e = rend[wid];
  float aa[8] = {0, 0, 0, 0, 0, 0, 0, 0};
  float bb[8] = {0, 0, 0, 0, 0, 0, 0, 0};
  for (int p = s + eg; p < e; p += EG) {
    int r = csr_row[p];
    float w = csr_w[p];
    uint4 v = *(const uint4*)(hp + (size_t)r * FIN + fl * 8);
    float f[8]; unpack8(v, f);
    #pragma unroll
    for (int i = 0; i < 8; ++i) { aa[i] += f[i] * w; bb[i] += f[i]; }
  }
  #pragma unroll
  for (int off = LPF; off < 64; off <<= 1) {
    #pragma unroll
    for (int i = 0; i < 8; ++i) {
      aa[i] += __shfl_xor(aa[i], off);
      bb[i] += __shfl_xor(bb[i], off);
    }
  }
  if (eg == 0) {
    float eps1 = 1.0f + epsp[0];
    uint4 hv = *(const uint4*)(hp + (size_t)wid * FIN + fl * 8);
    float hm[8]; unpack8(hv, hm);
    uint4 pa, pm;
    float m[8];
    #pragma unroll
    for (int i = 0; i < 8; ++i) m[i] = eps1 * hm[i] + bb[i];
    pa.x = f2bf(aa[0]) | ((u32)f2bf(aa[1]) << 16);
    pa.y = f2bf(aa[2]) | ((u32)f2bf(aa[3]) << 16);
    pa.z = f2bf(aa[4]) | ((u32)f2bf(aa[5]) << 16);
    pa.w = f2bf(aa[6]) | ((u32)f2bf(aa[7]) << 16);
    pm.x = f2bf(m[0]) | ((u32)f2bf(m[1]) << 16);
    pm.y = f2bf(m[2]) | ((u32)f2bf(m[3]) << 16);
    pm.z = f2bf(m[4]) | ((u32)f2bf(m[5]) << 16);
    pm.w = f2bf(m[6]) | ((u32)f2bf(m[7]) << 16);
    *(uint4*)(Aout + (size_t)wid * (2 * FIN) + fl * 8) = pa;
    *(uint4*)(Aout + (size_t)wid * (2 * FIN) + FIN + fl * 8) = pm;
  }
}

// ---------------- MFMA node update: 16 nodes per wave ----------------
// Ain rows (stride 2*FIN bf16): [AGG | M]. Output rows (stride 2*FOUT bf16):
// [lrelu(AGG@W+gb) | relu(relu(M@W1+b1)@W2+b2)].

template <int FIN, int FOUT>
__global__ __launch_bounds__(256) void k_nodeM(
    const u16* __restrict__ Ain, u16* __restrict__ ho,
    const float* __restrict__ gw, const float* __restrict__ gb,
    const float* __restrict__ w1, const float* __restrict__ b1,
    const float* __restrict__ w2, const float* __restrict__ b2, int n) {
  constexpr int AST = 2 * FIN;
  constexpr int HST = 2 * FOUT;
  constexpr int NKS = FIN / 32;
  constexpr int NJT = FOUT / 16;
  __shared__ __align__(16) u16 Wt[FOUT * FIN];   // Wt[j][k] = gw[k][j]
  __shared__ __align__(16) u16 W1t[16 * FIN];    // W1t[h][k] = w1[k][h], h>=10 -> 0
  __shared__ __align__(16) u16 W2t[FOUT * 32];   // W2t[j][k] = w2[k][j], k>=10 -> 0
  __shared__ __align__(16) u16 Tl[4][16][32];    // per-wave T tiles (k-padded 0)
  __shared__ float GBs[FOUT], B1s[16], B2s[FOUT];
  const int tid = threadIdx.x;
  for (int i = tid; i < FOUT * FIN; i += 256) {
    int j = i / FIN, k = i - j * FIN;
    Wt[i] = f2bf(gw[k * FOUT + j]);
  }
  for (int i = tid; i < 16 * FIN; i += 256) {
    int h = i / FIN, k = i - h * FIN;
    W1t[i] = (h < 10) ? f2bf(w1[k * 10 + h]) : (u16)0;
  }
  for (int i = tid; i < FOUT * 32; i += 256) {
    int j = i >> 5, k = i & 31;
    W2t[i] = (k < 10) ? f2bf(w2[k * FOUT + j]) : (u16)0;
  }
  for (int i = tid; i < FOUT; i += 256) { GBs[i] = gb[i]; B2s[i] = b2[i]; }
  if (tid < 16) B1s[tid] = (tid < 10) ? b1[tid] : 0.f;
  for (int i = tid; i < 4 * 16 * 32; i += 256) ((u16*)Tl)[i] = 0;
  __syncthreads();
  const int wid = tid >> 6, lane = tid & 63;
  const int c16 = lane & 15, kg = lane >> 4;
  const int ntile = n >> 4;  // n is a multiple of 16
  for (int t = blockIdx.x * 4 + wid; t < ntile; t += gridDim.x * 4) {
    const int nb = t << 4;
    const u16* arow = Ain + (size_t)(nb + c16) * AST;
    bf16x8 aA[NKS], aM[NKS];
    #pragma unroll
    for (int ks = 0; ks < NKS; ++ks) {
      aA[ks] = *(const bf16x8*)(arow + ks * 32 + kg * 8);
      aM[ks] = *(const bf16x8*)(arow + FIN + ks * 32 + kg * 8);
    }
    // GIN hidden: T = relu(M @ W1 + b1)   [16 x 16(10)]
    f32x4 tacc = {0.f, 0.f, 0.f, 0.f};
    #pragma unroll
    for (int ks = 0; ks < NKS; ++ks) {
      bf16x8 b = *(const bf16x8*)&W1t[c16 * FIN + ks * 32 + kg * 8];
      tacc = __builtin_amdgcn_mfma_f32_16x16x32_bf16(aM[ks], b, tacc, 0, 0, 0);
    }
    #pragma unroll
    for (int r = 0; r < 4; ++r)
      Tl[wid][kg * 4 + r][c16] = f2bf(fmaxf(tacc[r] + B1s[c16], 0.f));
    __builtin_amdgcn_sched_barrier(0);
    // GCN: lrelu(AGG @ W + gb)
    #pragma unroll
    for (int jt = 0; jt < NJT; ++jt) {
      f32x4 acc = {0.f, 0.f, 0.f, 0.f};
      #pragma unroll
      for (int ks = 0; ks < NKS; ++ks) {
        bf16x8 b = *(const bf16x8*)&Wt[(jt * 16 + c16) * FIN + ks * 32 + kg * 8];
        acc = __builtin_amdgcn_mfma_f32_16x16x32_bf16(aA[ks], b, acc, 0, 0, 0);
      }
      int colj = jt * 16 + c16;
      #pragma unroll
      for (int r = 0; r < 4; ++r) {
        int nd = nb + kg * 4 + r;
        ho[(size_t)nd * HST + colj] = f2bf(lrelu(acc[r] + GBs[colj]));
      }
    }
    // GIN out: relu(T @ W2 + b2), K = 32 (10 real + 22 zero)
    bf16x8 at = *(const bf16x8*)&Tl[wid][c16][kg * 8];
    #pragma unroll
    for (int jt = 0; jt < NJT; ++jt) {
      f32x4 acc = {0.f, 0.f, 0.f, 0.f};
      bf16x8 b = *(const bf16x8*)&W2t[(jt * 16 + c16) * 32 + kg * 8];
      acc = __builtin_amdgcn_mfma_f32_16x16x32_bf16(at, b, acc, 0, 0, 0);
      int colj = jt * 16 + c16;
      #pragma unroll
      for (int r = 0; r < 4; ++r) {
        int nd = nb + kg * 4 + r;
        ho[(size_t)nd * HST + FOUT + colj] = f2bf(fmaxf(acc[r] + B2s[colj], 0.f));
      }
    }
  }
}

// ---------------- GAT + pool ----------------

__global__ __launch_bounds__(256) void k_hjb(const u16* __restrict__ h3,
                                             const float* __restrict__ gw,
                                             float* __restrict__ hj, int n) {
  int wid = blockIdx.x * 4 + (threadIdx.x >> 6);
  if (wid >= n) return;
  int lane = threadIdx.x & 63;
  const u16* r = h3 + (size_t)wid * 256 + lane * 4;
  uint2 v = *(const uint2*)r;
  float acc = bf2f(v.x & 0xffff) * gw[lane * 4] + bf2f(v.x >> 16) * gw[lane * 4 + 1] +
              bf2f(v.y & 0xffff) * gw[lane * 4 + 2] + bf2f(v.y >> 16) * gw[lane * 4 + 3];
  for (int o = 32; o > 0; o >>= 1) acc += __shfl_down(acc, o);
  if (lane == 0) hj[wid] = acc;
}

__global__ void k_edge_max(const int* __restrict__ row, const float* __restrict__ hj,
                           const float* __restrict__ att, float* __restrict__ red, int ne) {
  float a = att[0];
  float m = -INFINITY;
  for (int e = blockIdx.x * blockDim.x + threadIdx.x; e < ne; e += gridDim.x * blockDim.x) {
    m = fmaxf(m, lrelu(a * hj[row[e]]));
  }
  for (int o = 32; o > 0; o >>= 1) m = fmaxf(m, __shfl_down(m, o));
  if ((threadIdx.x & 63) == 0) atomicMaxF(&red[6], m);
}

__global__ void k_gat(const int* __restrict__ rend, const int* __restrict__ csr_row,
                      const float* __restrict__ hj, const float* __restrict__ att,
                      float* __restrict__ red, float* __restrict__ scat, int n) {
  int c = blockIdx.x * 256 + threadIdx.x;
  float a = att[0];
  float m = red[6];
  float lsum = 0.f;
  if (c < n) {
    int s = (c == 0) ? 0 : rend[c - 1];
    int e = rend[c];
    float acc = 0.f;
    for (int p = s; p < e; ++p) {
      float h = hj[csr_row[p]];
      float pex = expf(lrelu(a * h) - m);
      lsum += pex;
      acc += pex * h;
    }
    scat[c] = acc;
  }
  for (int o = 32; o > 0; o >>= 1) lsum += __shfl_down(lsum, o);
  if ((threadIdx.x & 63) == 0) atomicAdd(&red[7], lsum);
}

__global__ __launch_bounds__(256) void k_pool(
    const u16* __restrict__ h3, const float* __restrict__ scat, const float* __restrict__ red,
    const float* __restrict__ lw, const float* __restrict__ lb,
    const float* __restrict__ l2w, const float* __restrict__ l2b,
    float* __restrict__ out, int ng) {
  __shared__ float pooled[256];
  __shared__ float aw[NPGC];
  __shared__ float y[10];
  int g = blockIdx.x;
  if (g >= ng) return;
  int tid = threadIdx.x;
  float inv_sexp = 1.0f / red[7];
  if (tid < NPGC) aw[tid] = scat[g * NPGC + tid] * inv_sexp;
  __syncthreads();
  const u16* base = h3 + (size_t)g * NPGC * 256;
  float acc = 0.f;
  #pragma unroll
  for (int u = 0; u < NPGC; ++u) acc += bf2f(base[u * 256 + tid]) * aw[u];
  pooled[tid] = acc * (1.0f / NPGC);
  __syncthreads();
  if (tid < 10) {
    float s = lb[tid];
    for (int f = 0; f < 256; ++f) s += pooled[f] * lw[f * 10 + tid];
    y[tid] = s;
  }
  __syncthreads();
  if (tid == 0) {
    float s = l2b[0];
    #pragma unroll
    for (int k = 0; k < 10; ++k) s += y[k] * l2w[k];
    out[g] = 1.0f / (1.0f + expf(-s));
  }
}

extern "C" void kernel_launch(void* const* d_in, const int* in_sizes, int n_in,
                              void* d_out, int out_size, void* d_ws, size_t ws_size,
                              hipStream_t stream) {
  const float* x        = (const float*)d_in[0];
  const int*   eidx     = (const int*)d_in[1];
  const float* ew       = (const float*)d_in[2];
  const float* gcn1_w   = (const float*)d_in[3];
  const float* gcn1_b   = (const float*)d_in[4];
  const float* gcn2_w   = (const float*)d_in[5];
  const float* gcn2_b   = (const float*)d_in[6];
  const float* gcn3_w   = (const float*)d_in[7];
  const float* gcn3_b   = (const float*)d_in[8];
  const float* gin1_w1  = (const float*)d_in[9];
  const float* gin1_b1  = (const float*)d_in[10];
  const float* gin1_w2  = (const float*)d_in[11];
  const float* gin1_b2  = (const float*)d_in[12];
  const float* gin1_eps = (const float*)d_in[13];
  const float* gin2_w1  = (const float*)d_in[14];
  const float* gin2_b1  = (const float*)d_in[15];
  const float* gin2_w2  = (const float*)d_in[16];
  const float* gin2_b2  = (const float*)d_in[17];
  const float* gin2_eps = (const float*)d_in[18];
  const float* gin3_w1  = (const float*)d_in[19];
  const float* gin3_b1  = (const float*)d_in[20];
  const float* gin3_w2  = (const float*)d_in[21];
  const float* gin3_b2  = (const float*)d_in[22];
  const float* gin3_eps = (const float*)d_in[23];
  const float* gat_w    = (const float*)d_in[24];
  const float* gat_att  = (const float*)d_in[25];
  const float* lin_w    = (const float*)d_in[26];
  const float* lin_b    = (const float*)d_in[27];
  const float* lin2_w   = (const float*)d_in[28];
  const float* lin2_b   = (const float*)d_in[29];
  float* out = (float*)d_out;

  const int* row = eidx;
  const int* col = eidx + N_EDGES;

  // Workspace (bytes), peak ~202 MB:
  //  R1 [N*512 B]: {x0 f32 N*3 | agg1 f32 N*8 | h1 bf16 N*64} -> A3 bf16 N*256
  //  R2 [N*512 B]: {deg,bsum} -> A2 bf16 N*128 -> h3 bf16 N*256
  //  R3 [N*256 B]: h2 bf16 N*128 -> {hj f32 N | scat f32 N}
  //  persistent: rowptr[N], csr_row[E], csr_w[E], red[64]
  char* B = (char*)d_ws;
  float* x0     = (float*)B;
  float* agg1   = (float*)(B + (size_t)N_NODES * 12);
  u16*   h1     = (u16*)(B + (size_t)N_NODES * 44);
  u16*   A3     = (u16*)B;
  u16*   A2     = (u16*)(B + (size_t)N_NODES * 512);
  u16*   h3     = (u16*)(B + (size_t)N_NODES * 512);
  int*   deg    = (int*)(B + (size_t)N_NODES * 512);
  int*   bsum   = deg + N_NODES;
  u16*   h2     = (u16*)(B + (size_t)N_NODES * 1024);
  float* hj     = (float*)(B + (size_t)N_NODES * 1024);
  float* scat   = hj + N_NODES;
  int*   rowptr = (int*)(B + (size_t)N_NODES * 1280);
  int*   csr_row = rowptr + N_NODES;
  float* csr_w  = (float*)(csr_row + N_EDGES);
  float* red    = csr_w + N_EDGES;

  const int GE = (N_EDGES + 255) / 256;
  const int GN = (N_NODES + 255) / 256;
  const int GW = (N_NODES + 3) / 4;  // one wave per node

  // CSR build
  hipMemsetAsync(deg, 0, (size_t)N_NODES * 4, stream);
  hipLaunchKernelGGL(k_degree, dim3(GE), dim3(256), 0, stream, col, deg, N_EDGES);
  hipLaunchKernelGGL(k_scan1, dim3(NB_SCAN), dim3(256), 0, stream, deg, rowptr, bsum, N_NODES);
  hipLaunchKernelGGL(k_scan2, dim3(1), dim3(256), 0, stream, bsum, NB_SCAN);
  hipLaunchKernelGGL(k_scan3, dim3(GN), dim3(256), 0, stream, rowptr, bsum, N_NODES);
  hipLaunchKernelGGL(k_fill, dim3(GE), dim3(256), 0, stream, row, col, ew, rowptr, csr_row, csr_w, N_EDGES);

  // normalization
  hipLaunchKernelGGL(k_init, dim3(1), dim3(64), 0, stream, red);
  hipLaunchKernelGGL(k_colstats, dim3(256), dim3(256), 0, stream, x, red, N_NODES);
  hipLaunchKernelGGL(k_norm, dim3((N_NODES * 3 + 255) / 256), dim3(256), 0, stream, x, red, x0, N_NODES);

  // layer 1: 3 -> 32|32
  hipLaunchKernelGGL(k_gather3, dim3(GN), dim3(256), 0, stream,
                     x0, rowptr, csr_row, csr_w, gin1_eps, agg1, N_NODES);
  hipLaunchKernelGGL(k_node1, dim3(GN), dim3(256), 0, stream,
                     agg1, h1, gcn1_w, gcn1_b, gin1_w1, gin1_b1, gin1_w2, gin1_b2, N_NODES);

  // layer 2: 64 -> 64|64
  hipLaunchKernelGGL((k_spmmb<64>), dim3(GW), dim3(256), 0, stream,
                     h1, A2, rowptr, csr_row, csr_w, gin2_eps, N_NODES);
  hipLaunchKernelGGL((k_nodeM<64, 64>), dim3(512), dim3(256), 0, stream,
                     A2, h2, gcn2_w, gcn2_b, gin2_w1, gin2_b1, gin2_w2, gin2_b2, N_NODES);

  // layer 3: 128 -> 128|128
  hipLaunchKernelGGL((k_spmmb<128>), dim3(GW), dim3(256), 0, stream,
                     h2, A3, rowptr, csr_row, csr_w, gin3_eps, N_NODES);
  hipLaunchKernelGGL((k_nodeM<128, 128>), dim3(512), dim3(256), 0, stream,
                     A3, h3, gcn3_w, gcn3_b, gin3_w1, gin3_b1, gin3_w2, gin3_b2, N_NODES);

  // GAT
  hipLaunchKernelGGL(k_hjb, dim3(GW), dim3(256), 0, stream, h3, gat_w, hj, N_NODES);
  hipLaunchKernelGGL(k_edge_max, dim3(1024), dim3(256), 0, stream, row, hj, gat_att, red, N_EDGES);
  hipLaunchKernelGGL(k_gat, dim3(GN), dim3(256), 0, stream, rowptr, csr_row, hj, gat_att, red, scat, N_NODES);

  // pool + readout
  hipLaunchKernelGGL(k_pool, dim3(NGRAPH), dim3(256), 0, stream,
                     h3, scat, red, lin_w, lin_b, lin2_w, lin2_b, out, NGRAPH);
}

// Round 6
// 492.459 us; speedup vs baseline: 5.8787x; 1.2810x over previous
//
#include <hip/hip_runtime.h>
#include <hip/hip_bf16.h>
#include <math.h>

constexpr int N_NODES = 150000;
constexpr int N_EDGES = 1200000;
constexpr int NPGC    = 30;
constexpr int NGRAPH  = N_NODES / NPGC;
constexpr int NB_SCAN = (N_NODES + 1023) / 1024;
constexpr int RB      = 256;   // reduction grid size (partials per stage-1 kernel)

typedef unsigned int u32;
typedef unsigned short u16;
typedef __attribute__((ext_vector_type(8))) short bf16x8;
typedef __attribute__((ext_vector_type(4))) float f32x4;

__device__ __forceinline__ float lrelu(float v) { return v > 0.f ? v : 0.2f * v; }
__device__ __forceinline__ float bf2f(u32 h) { return __uint_as_float(h << 16); }
__device__ __forceinline__ u16 f2bf(float f) {
  u32 u = __float_as_uint(f);
  return (u16)((u + 0x7FFFu + ((u >> 16) & 1u)) >> 16);
}
__device__ __forceinline__ void unpack8(uint4 v, float* f) {
  f[0] = bf2f(v.x & 0xffff); f[1] = bf2f(v.x >> 16);
  f[2] = bf2f(v.y & 0xffff); f[3] = bf2f(v.y >> 16);
  f[4] = bf2f(v.z & 0xffff); f[5] = bf2f(v.z >> 16);
  f[6] = bf2f(v.w & 0xffff); f[7] = bf2f(v.w >> 16);
}

// ---------------- CSR build ----------------

__global__ void k_degree(const int* __restrict__ col, int* __restrict__ deg, int ne) {
  int e = blockIdx.x * 256 + threadIdx.x;
  if (e < ne) atomicAdd(&deg[col[e]], 1);
}

__global__ __launch_bounds__(256) void k_scan1(const int* __restrict__ deg,
                                               int* __restrict__ rowptr,
                                               int* __restrict__ bsum, int n) {
  __shared__ int ts[256];
  int b = blockIdx.x, tid = threadIdx.x;
  int base = b * 1024 + tid * 4;
  int d[4]; int s = 0;
  #pragma unroll
  for (int k = 0; k < 4; ++k) { d[k] = (base + k < n) ? deg[base + k] : 0; s += d[k]; }
  ts[tid] = s;
  __syncthreads();
  for (int off = 1; off < 256; off <<= 1) {
    int v = (tid >= off) ? ts[tid - off] : 0;
    __syncthreads();
    ts[tid] += v;
    __syncthreads();
  }
  int run = ts[tid] - s;
  #pragma unroll
  for (int k = 0; k < 4; ++k) {
    if (base + k < n) rowptr[base + k] = run;
    run += d[k];
  }
  if (tid == 255) bsum[b] = ts[255];
}

__global__ __launch_bounds__(256) void k_scan2(int* __restrict__ bsum, int nb) {
  __shared__ int ts[256];
  int tid = threadIdx.x;
  int orig = (tid < nb) ? bsum[tid] : 0;
  ts[tid] = orig;
  __syncthreads();
  for (int off = 1; off < 256; off <<= 1) {
    int v = (tid >= off) ? ts[tid - off] : 0;
    __syncthreads();
    ts[tid] += v;
    __syncthreads();
  }
  if (tid < nb) bsum[tid] = ts[tid] - orig;
}

__global__ void k_scan3(int* __restrict__ rowptr, const int* __restrict__ bsum, int n) {
  int i = blockIdx.x * 256 + threadIdx.x;
  if (i < n) rowptr[i] += bsum[i >> 10];
}

__global__ void k_fill(const int* __restrict__ row, const int* __restrict__ col,
                       const float* __restrict__ ew, int* __restrict__ rowptr,
                       int* __restrict__ csr_row, float* __restrict__ csr_w, int ne) {
  int e = blockIdx.x * 256 + threadIdx.x;
  if (e >= ne) return;
  int c = col[e];
  int p = atomicAdd(&rowptr[c], 1);
  csr_row[p] = row[e];
  csr_w[p] = ew[e];
}

// ---------------- normalization (two-stage, no contended atomics) ----------------
// red layout: [0..2] colsum, [3..5] colmax, [6] softmax max, [7] softmax sumexp

__global__ __launch_bounds__(256) void k_cs1(const float* __restrict__ x,
                                             float* __restrict__ pb, int n) {
  __shared__ float ls[4][6];
  float s0 = 0, s1 = 0, s2 = 0;
  float m0 = -INFINITY, m1 = -INFINITY, m2 = -INFINITY;
  for (int i = blockIdx.x * 256 + threadIdx.x; i < n; i += RB * 256) {
    float v0 = x[3 * i], v1 = x[3 * i + 1], v2 = x[3 * i + 2];
    s0 += v0; s1 += v1; s2 += v2;
    m0 = fmaxf(m0, v0); m1 = fmaxf(m1, v1); m2 = fmaxf(m2, v2);
  }
  for (int o = 32; o > 0; o >>= 1) {
    s0 += __shfl_down(s0, o); s1 += __shfl_down(s1, o); s2 += __shfl_down(s2, o);
    m0 = fmaxf(m0, __shfl_down(m0, o));
    m1 = fmaxf(m1, __shfl_down(m1, o));
    m2 = fmaxf(m2, __shfl_down(m2, o));
  }
  int w = threadIdx.x >> 6;
  if ((threadIdx.x & 63) == 0) {
    ls[w][0] = s0; ls[w][1] = s1; ls[w][2] = s2;
    ls[w][3] = m0; ls[w][4] = m1; ls[w][5] = m2;
  }
  __syncthreads();
  if (threadIdx.x == 0) {
    float* o = pb + blockIdx.x * 8;
    o[0] = ls[0][0] + ls[1][0] + ls[2][0] + ls[3][0];
    o[1] = ls[0][1] + ls[1][1] + ls[2][1] + ls[3][1];
    o[2] = ls[0][2] + ls[1][2] + ls[2][2] + ls[3][2];
    o[3] = fmaxf(fmaxf(ls[0][3], ls[1][3]), fmaxf(ls[2][3], ls[3][3]));
    o[4] = fmaxf(fmaxf(ls[0][4], ls[1][4]), fmaxf(ls[2][4], ls[3][4]));
    o[5] = fmaxf(fmaxf(ls[0][5], ls[1][5]), fmaxf(ls[2][5], ls[3][5]));
  }
}

__global__ __launch_bounds__(256) void k_cs2(const float* __restrict__ pb,
                                             float* __restrict__ red) {
  __shared__ float ls[4][6];
  int tid = threadIdx.x;
  const float* p = pb + tid * 8;
  float s0 = p[0], s1 = p[1], s2 = p[2], m0 = p[3], m1 = p[4], m2 = p[5];
  for (int o = 32; o > 0; o >>= 1) {
    s0 += __shfl_down(s0, o); s1 += __shfl_down(s1, o); s2 += __shfl_down(s2, o);
    m0 = fmaxf(m0, __shfl_down(m0, o));
    m1 = fmaxf(m1, __shfl_down(m1, o));
    m2 = fmaxf(m2, __shfl_down(m2, o));
  }
  int w = tid >> 6;
  if ((tid & 63) == 0) {
    ls[w][0] = s0; ls[w][1] = s1; ls[w][2] = s2;
    ls[w][3] = m0; ls[w][4] = m1; ls[w][5] = m2;
  }
  __syncthreads();
  if (tid == 0) {
    red[0] = ls[0][0] + ls[1][0] + ls[2][0] + ls[3][0];
    red[1] = ls[0][1] + ls[1][1] + ls[2][1] + ls[3][1];
    red[2] = ls[0][2] + ls[1][2] + ls[2][2] + ls[3][2];
    red[3] = fmaxf(fmaxf(ls[0][3], ls[1][3]), fmaxf(ls[2][3], ls[3][3]));
    red[4] = fmaxf(fmaxf(ls[0][4], ls[1][4]), fmaxf(ls[2][4], ls[3][4]));
    red[5] = fmaxf(fmaxf(ls[0][5], ls[1][5]), fmaxf(ls[2][5], ls[3][5]));
  }
}

__global__ void k_norm(const float* __restrict__ x, const float* __restrict__ red,
                       float* __restrict__ x0, int n) {
  int i = blockIdx.x * 256 + threadIdx.x;
  if (i >= n * 3) return;
  int c = i % 3;
  float mean = red[c] / (float)n;
  float denom = red[3 + c] - mean;   // max(x - mean) = max(x) - mean
  x0[i] = (x[i] - mean) / denom;
}

// ---------------- layer 1 ----------------

__global__ void k_gather3(const float* __restrict__ x0, const int* __restrict__ rend,
                          const int* __restrict__ csr_row, const float* __restrict__ csr_w,
                          const float* __restrict__ epsp, float* __restrict__ agg1, int n) {
  int c = blockIdx.x * 256 + threadIdx.x;
  if (c >= n) return;
  int s = (c == 0) ? 0 : rend[c - 1];
  int e = rend[c];
  float a0 = 0, a1 = 0, a2 = 0, b0 = 0, b1 = 0, b2 = 0;
  for (int p = s; p < e; ++p) {
    int r = csr_row[p];
    float w = csr_w[p];
    float v0 = x0[3 * r], v1 = x0[3 * r + 1], v2 = x0[3 * r + 2];
    a0 += v0 * w; a1 += v1 * w; a2 += v2 * w;
    b0 += v0; b1 += v1; b2 += v2;
  }
  float eps1 = 1.0f + epsp[0];
  float* ap = agg1 + (size_t)c * 8;
  ap[0] = a0; ap[1] = a1; ap[2] = a2;
  ap[3] = eps1 * x0[3 * c] + b0;
  ap[4] = eps1 * x0[3 * c + 1] + b1;
  ap[5] = eps1 * x0[3 * c + 2] + b2;
}

__global__ __launch_bounds__(256) void k_node1(
    const float* __restrict__ agg1, u16* __restrict__ h1,
    const float* __restrict__ gw, const float* __restrict__ gb,
    const float* __restrict__ w1, const float* __restrict__ b1,
    const float* __restrict__ w2, const float* __restrict__ b2, int n) {
  __shared__ float Ws[96], W1s[30], W2s[320], GBs[32], B1s[10], B2s[32];
  int tid = threadIdx.x;
  if (tid < 96) Ws[tid] = gw[tid];
  if (tid < 30) W1s[tid] = w1[tid];
  for (int i = tid; i < 320; i += 256) W2s[i] = w2[i];
  if (tid < 32) { GBs[tid] = gb[tid]; B2s[tid] = b2[tid]; }
  if (tid < 10) B1s[tid] = b1[tid];
  __syncthreads();
  int nd = blockIdx.x * 256 + tid;
  if (nd >= n) return;
  const float* a = agg1 + (size_t)nd * 8;
  float a0 = a[0], a1 = a[1], a2 = a[2], m0 = a[3], m1 = a[4], m2 = a[5];
  float t[10];
  #pragma unroll
  for (int h = 0; h < 10; ++h)
    t[h] = fmaxf(B1s[h] + m0 * W1s[h] + m1 * W1s[10 + h] + m2 * W1s[20 + h], 0.f);
  u32 w_[32];
  #pragma unroll
  for (int j = 0; j < 32; ++j) {
    float v = lrelu(GBs[j] + a0 * Ws[j] + a1 * Ws[32 + j] + a2 * Ws[64 + j]);
    u32 bv = f2bf(v);
    if (j & 1) w_[j >> 1] |= bv << 16; else w_[j >> 1] = bv;
  }
  #pragma unroll
  for (int j = 0; j < 32; ++j) {
    float s = B2s[j];
    #pragma unroll
    for (int h = 0; h < 10; ++h) s += t[h] * W2s[h * 32 + j];
    u32 bv = f2bf(fmaxf(s, 0.f));
    int jj = 32 + j;
    if (jj & 1) w_[jj >> 1] |= bv << 16; else w_[jj >> 1] = bv;
  }
  uint4* dst = (uint4*)(h1 + (size_t)nd * 64);
  #pragma unroll
  for (int q = 0; q < 8; ++q) {
    uint4 v; v.x = w_[q * 4]; v.y = w_[q * 4 + 1]; v.z = w_[q * 4 + 2]; v.w = w_[q * 4 + 3];
    dst[q] = v;
  }
}

// ---------------- bf16 edge-parallel SpMM: one wave per node ----------------

template <int FIN>
__global__ __launch_bounds__(256) void k_spmmb(
    const u16* __restrict__ hp, u16* __restrict__ Aout,
    const int* __restrict__ rend, const int* __restrict__ csr_row,
    const float* __restrict__ csr_w, const float* __restrict__ epsp, int n) {
  constexpr int LPF = FIN / 8;
  constexpr int EG  = 64 / LPF;
  int wid = (blockIdx.x * 256 + threadIdx.x) >> 6;
  if (wid >= n) return;
  int lane = threadIdx.x & 63;
  int fl = lane & (LPF - 1);
  int eg = lane / LPF;
  int s = (wid == 0) ? 0 : rend[wid - 1];
  int e = rend[wid];
  float aa[8] = {0, 0, 0, 0, 0, 0, 0, 0};
  float bb[8] = {0, 0, 0, 0, 0, 0, 0, 0};
  for (int p = s + eg; p < e; p += EG) {
    int r = csr_row[p];
    float w = csr_w[p];
    uint4 v = *(const uint4*)(hp + (size_t)r * FIN + fl * 8);
    float f[8]; unpack8(v, f);
    #pragma unroll
    for (int i = 0; i < 8; ++i) { aa[i] += f[i] * w; bb[i] += f[i]; }
  }
  #pragma unroll
  for (int off = LPF; off < 64; off <<= 1) {
    #pragma unroll
    for (int i = 0; i < 8; ++i) {
      aa[i] += __shfl_xor(aa[i], off);
      bb[i] += __shfl_xor(bb[i], off);
    }
  }
  if (eg == 0) {
    float eps1 = 1.0f + epsp[0];
    uint4 hv = *(const uint4*)(hp + (size_t)wid * FIN + fl * 8);
    float hm[8]; unpack8(hv, hm);
    uint4 pa, pm;
    float m[8];
    #pragma unroll
    for (int i = 0; i < 8; ++i) m[i] = eps1 * hm[i] + bb[i];
    pa.x = f2bf(aa[0]) | ((u32)f2bf(aa[1]) << 16);
    pa.y = f2bf(aa[2]) | ((u32)f2bf(aa[3]) << 16);
    pa.z = f2bf(aa[4]) | ((u32)f2bf(aa[5]) << 16);
    pa.w = f2bf(aa[6]) | ((u32)f2bf(aa[7]) << 16);
    pm.x = f2bf(m[0]) | ((u32)f2bf(m[1]) << 16);
    pm.y = f2bf(m[2]) | ((u32)f2bf(m[3]) << 16);
    pm.z = f2bf(m[4]) | ((u32)f2bf(m[5]) << 16);
    pm.w = f2bf(m[6]) | ((u32)f2bf(m[7]) << 16);
    *(uint4*)(Aout + (size_t)wid * (2 * FIN) + fl * 8) = pa;
    *(uint4*)(Aout + (size_t)wid * (2 * FIN) + FIN + fl * 8) = pm;
  }
}

// ---------------- MFMA node update: 16 nodes per wave ----------------

template <int FIN, int FOUT>
__global__ __launch_bounds__(256) void k_nodeM(
    const u16* __restrict__ Ain, u16* __restrict__ ho,
    const float* __restrict__ gw, const float* __restrict__ gb,
    const float* __restrict__ w1, const float* __restrict__ b1,
    const float* __restrict__ w2, const float* __restrict__ b2, int n) {
  constexpr int AST = 2 * FIN;
  constexpr int HST = 2 * FOUT;
  constexpr int NKS = FIN / 32;
  constexpr int NJT = FOUT / 16;
  __shared__ __align__(16) u16 Wt[FOUT * FIN];
  __shared__ __align__(16) u16 W1t[16 * FIN];
  __shared__ __align__(16) u16 W2t[FOUT * 32];
  __shared__ __align__(16) u16 Tl[4][16][32];
  __shared__ float GBs[FOUT], B1s[16], B2s[FOUT];
  const int tid = threadIdx.x;
  for (int i = tid; i < FOUT * FIN; i += 256) {
    int j = i / FIN, k = i - j * FIN;
    Wt[i] = f2bf(gw[k * FOUT + j]);
  }
  for (int i = tid; i < 16 * FIN; i += 256) {
    int h = i / FIN, k = i - h * FIN;
    W1t[i] = (h < 10) ? f2bf(w1[k * 10 + h]) : (u16)0;
  }
  for (int i = tid; i < FOUT * 32; i += 256) {
    int j = i >> 5, k = i & 31;
    W2t[i] = (k < 10) ? f2bf(w2[k * FOUT + j]) : (u16)0;
  }
  for (int i = tid; i < FOUT; i += 256) { GBs[i] = gb[i]; B2s[i] = b2[i]; }
  if (tid < 16) B1s[tid] = (tid < 10) ? b1[tid] : 0.f;
  for (int i = tid; i < 4 * 16 * 32; i += 256) ((u16*)Tl)[i] = 0;
  __syncthreads();
  const int wid = tid >> 6, lane = tid & 63;
  const int c16 = lane & 15, kg = lane >> 4;
  const int ntile = n >> 4;
  for (int t = blockIdx.x * 4 + wid; t < ntile; t += gridDim.x * 4) {
    const int nb = t << 4;
    const u16* arow = Ain + (size_t)(nb + c16) * AST;
    bf16x8 aA[NKS], aM[NKS];
    #pragma unroll
    for (int ks = 0; ks < NKS; ++ks) {
      aA[ks] = *(const bf16x8*)(arow + ks * 32 + kg * 8);
      aM[ks] = *(const bf16x8*)(arow + FIN + ks * 32 + kg * 8);
    }
    f32x4 tacc = {0.f, 0.f, 0.f, 0.f};
    #pragma unroll
    for (int ks = 0; ks < NKS; ++ks) {
      bf16x8 b = *(const bf16x8*)&W1t[c16 * FIN + ks * 32 + kg * 8];
      tacc = __builtin_amdgcn_mfma_f32_16x16x32_bf16(aM[ks], b, tacc, 0, 0, 0);
    }
    #pragma unroll
    for (int r = 0; r < 4; ++r)
      Tl[wid][kg * 4 + r][c16] = f2bf(fmaxf(tacc[r] + B1s[c16], 0.f));
    __builtin_amdgcn_sched_barrier(0);
    #pragma unroll
    for (int jt = 0; jt < NJT; ++jt) {
      f32x4 acc = {0.f, 0.f, 0.f, 0.f};
      #pragma unroll
      for (int ks = 0; ks < NKS; ++ks) {
        bf16x8 b = *(const bf16x8*)&Wt[(jt * 16 + c16) * FIN + ks * 32 + kg * 8];
        acc = __builtin_amdgcn_mfma_f32_16x16x32_bf16(aA[ks], b, acc, 0, 0, 0);
      }
      int colj = jt * 16 + c16;
      #pragma unroll
      for (int r = 0; r < 4; ++r) {
        int nd = nb + kg * 4 + r;
        ho[(size_t)nd * HST + colj] = f2bf(lrelu(acc[r] + GBs[colj]));
      }
    }
    bf16x8 at = *(const bf16x8*)&Tl[wid][c16][kg * 8];
    #pragma unroll
    for (int jt = 0; jt < NJT; ++jt) {
      f32x4 acc = {0.f, 0.f, 0.f, 0.f};
      bf16x8 b = *(const bf16x8*)&W2t[(jt * 16 + c16) * 32 + kg * 8];
      acc = __builtin_amdgcn_mfma_f32_16x16x32_bf16(at, b, acc, 0, 0, 0);
      int colj = jt * 16 + c16;
      #pragma unroll
      for (int r = 0; r < 4; ++r) {
        int nd = nb + kg * 4 + r;
        ho[(size_t)nd * HST + FOUT + colj] = f2bf(fmaxf(acc[r] + B2s[colj], 0.f));
      }
    }
  }
}

// ---------------- GAT + pool ----------------

__global__ __launch_bounds__(256) void k_hjb(const u16* __restrict__ h3,
                                             const float* __restrict__ gw,
                                             float* __restrict__ hj, int n) {
  int wid = blockIdx.x * 4 + (threadIdx.x >> 6);
  if (wid >= n) return;
  int lane = threadIdx.x & 63;
  const u16* r = h3 + (size_t)wid * 256 + lane * 4;
  uint2 v = *(const uint2*)r;
  float acc = bf2f(v.x & 0xffff) * gw[lane * 4] + bf2f(v.x >> 16) * gw[lane * 4 + 1] +
              bf2f(v.y & 0xffff) * gw[lane * 4 + 2] + bf2f(v.y >> 16) * gw[lane * 4 + 3];
  for (int o = 32; o > 0; o >>= 1) acc += __shfl_down(acc, o);
  if (lane == 0) hj[wid] = acc;
}

// stage-1 edge max -> per-block partials (no contended atomics)
__global__ __launch_bounds__(256) void k_em1(const int* __restrict__ row,
                                             const float* __restrict__ hj,
                                             const float* __restrict__ att,
                                             float* __restrict__ pb, int ne) {
  __shared__ float ls[4];
  float a = att[0];
  float m = -INFINITY;
  for (int e = blockIdx.x * 256 + threadIdx.x; e < ne; e += RB * 256) {
    m = fmaxf(m, lrelu(a * hj[row[e]]));
  }
  for (int o = 32; o > 0; o >>= 1) m = fmaxf(m, __shfl_down(m, o));
  int w = threadIdx.x >> 6;
  if ((threadIdx.x & 63) == 0) ls[w] = m;
  __syncthreads();
  if (threadIdx.x == 0)
    pb[blockIdx.x] = fmaxf(fmaxf(ls[0], ls[1]), fmaxf(ls[2], ls[3]));
}

__global__ __launch_bounds__(256) void k_em2(const float* __restrict__ pb,
                                             float* __restrict__ red) {
  __shared__ float ls[4];
  int tid = threadIdx.x;
  float m = pb[tid];
  for (int o = 32; o > 0; o >>= 1) m = fmaxf(m, __shfl_down(m, o));
  int w = tid >> 6;
  if ((tid & 63) == 0) ls[w] = m;
  __syncthreads();
  if (tid == 0) red[6] = fmaxf(fmaxf(ls[0], ls[1]), fmaxf(ls[2], ls[3]));
}

// per-node gather of unnormalized att_weight; per-block partial sumexp
__global__ __launch_bounds__(256) void k_gat(const int* __restrict__ rend,
                                             const int* __restrict__ csr_row,
                                             const float* __restrict__ hj,
                                             const float* __restrict__ att,
                                             const float* __restrict__ red,
                                             float* __restrict__ scat,
                                             float* __restrict__ pb, int n) {
  __shared__ float ls[4];
  float a = att[0];
  float m = red[6];
  float lsum = 0.f;
  for (int c = blockIdx.x * 256 + threadIdx.x; c < n; c += RB * 256) {
    int s = (c == 0) ? 0 : rend[c - 1];
    int e = rend[c];
    float acc = 0.f;
    for (int p = s; p < e; ++p) {
      float h = hj[csr_row[p]];
      float pex = expf(lrelu(a * h) - m);
      lsum += pex;
      acc += pex * h;
    }
    scat[c] = acc;
  }
  for (int o = 32; o > 0; o >>= 1) lsum += __shfl_down(lsum, o);
  int w = threadIdx.x >> 6;
  if ((threadIdx.x & 63) == 0) ls[w] = lsum;
  __syncthreads();
  if (threadIdx.x == 0) pb[blockIdx.x] = ls[0] + ls[1] + ls[2] + ls[3];
}

__global__ __launch_bounds__(256) void k_gsum(const float* __restrict__ pb,
                                              float* __restrict__ red) {
  __shared__ float ls[4];
  int tid = threadIdx.x;
  float s = pb[tid];
  for (int o = 32; o > 0; o >>= 1) s += __shfl_down(s, o);
  int w = tid >> 6;
  if ((tid & 63) == 0) ls[w] = s;
  __syncthreads();
  if (tid == 0) red[7] = ls[0] + ls[1] + ls[2] + ls[3];
}

__global__ __launch_bounds__(256) void k_pool(
    const u16* __restrict__ h3, const float* __restrict__ scat, const float* __restrict__ red,
    const float* __restrict__ lw, const float* __restrict__ lb,
    const float* __restrict__ l2w, const float* __restrict__ l2b,
    float* __restrict__ out, int ng) {
  __shared__ float pooled[256];
  __shared__ float aw[NPGC];
  __shared__ float y[10];
  int g = blockIdx.x;
  if (g >= ng) return;
  int tid = threadIdx.x;
  float inv_sexp = 1.0f / red[7];
  if (tid < NPGC) aw[tid] = scat[g * NPGC + tid] * inv_sexp;
  __syncthreads();
  const u16* base = h3 + (size_t)g * NPGC * 256;
  float acc = 0.f;
  #pragma unroll
  for (int u = 0; u < NPGC; ++u) acc += bf2f(base[u * 256 + tid]) * aw[u];
  pooled[tid] = acc * (1.0f / NPGC);
  __syncthreads();
  if (tid < 10) {
    float s = lb[tid];
    for (int f = 0; f < 256; ++f) s += pooled[f] * lw[f * 10 + tid];
    y[tid] = s;
  }
  __syncthreads();
  if (tid == 0) {
    float s = l2b[0];
    #pragma unroll
    for (int k = 0; k < 10; ++k) s += y[k] * l2w[k];
    out[g] = 1.0f / (1.0f + expf(-s));
  }
}

extern "C" void kernel_launch(void* const* d_in, const int* in_sizes, int n_in,
                              void* d_out, int out_size, void* d_ws, size_t ws_size,
                              hipStream_t stream) {
  const float* x        = (const float*)d_in[0];
  const int*   eidx     = (const int*)d_in[1];
  const float* ew       = (const float*)d_in[2];
  const float* gcn1_w   = (const float*)d_in[3];
  const float* gcn1_b   = (const float*)d_in[4];
  const float* gcn2_w   = (const float*)d_in[5];
  const float* gcn2_b   = (const float*)d_in[6];
  const float* gcn3_w   = (const float*)d_in[7];
  const float* gcn3_b   = (const float*)d_in[8];
  const float* gin1_w1  = (const float*)d_in[9];
  const float* gin1_b1  = (const float*)d_in[10];
  const float* gin1_w2  = (const float*)d_in[11];
  const float* gin1_b2  = (const float*)d_in[12];
  const float* gin1_eps = (const float*)d_in[13];
  const float* gin2_w1  = (const float*)d_in[14];
  const float* gin2_b1  = (const float*)d_in[15];
  const float* gin2_w2  = (const float*)d_in[16];
  const float* gin2_b2  = (const float*)d_in[17];
  const float* gin2_eps = (const float*)d_in[18];
  const float* gin3_w1  = (const float*)d_in[19];
  const float* gin3_b1  = (const float*)d_in[20];
  const float* gin3_w2  = (const float*)d_in[21];
  const float* gin3_b2  = (const float*)d_in[22];
  const float* gin3_eps = (const float*)d_in[23];
  const float* gat_w    = (const float*)d_in[24];
  const float* gat_att  = (const float*)d_in[25];
  const float* lin_w    = (const float*)d_in[26];
  const float* lin_b    = (const float*)d_in[27];
  const float* lin2_w   = (const float*)d_in[28];
  const float* lin2_b   = (const float*)d_in[29];
  float* out = (float*)d_out;

  const int* row = eidx;
  const int* col = eidx + N_EDGES;

  // Workspace (bytes), peak ~202 MB (same as round 5 + small partial buffers):
  //  R1 [N*512 B]: {x0 f32 N*3 | agg1 f32 N*8 | h1 bf16 N*64} -> A3 bf16 N*256
  //  R2 [N*512 B]: {deg,bsum} -> A2 bf16 N*128 -> h3 bf16 N*256
  //  R3 [N*256 B]: h2 bf16 N*128 -> {hj f32 N | scat f32 N}
  //  persistent: rowptr[N], csr_row[E], csr_w[E], red[64], pcs[2048], pem[256], pga[256]
  char* B = (char*)d_ws;
  float* x0     = (float*)B;
  float* agg1   = (float*)(B + (size_t)N_NODES * 12);
  u16*   h1     = (u16*)(B + (size_t)N_NODES * 44);
  u16*   A3     = (u16*)B;
  u16*   A2     = (u16*)(B + (size_t)N_NODES * 512);
  u16*   h3     = (u16*)(B + (size_t)N_NODES * 512);
  int*   deg    = (int*)(B + (size_t)N_NODES * 512);
  int*   bsum   = deg + N_NODES;
  u16*   h2     = (u16*)(B + (size_t)N_NODES * 1024);
  float* hj     = (float*)(B + (size_t)N_NODES * 1024);
  float* scat   = hj + N_NODES;
  int*   rowptr = (int*)(B + (size_t)N_NODES * 1280);
  int*   csr_row = rowptr + N_NODES;
  float* csr_w  = (float*)(csr_row + N_EDGES);
  float* red    = csr_w + N_EDGES;
  float* pcs    = red + 64;        // RB*8
  float* pem    = pcs + RB * 8;    // RB
  float* pga    = pem + RB;        // RB

  const int GE = (N_EDGES + 255) / 256;
  const int GN = (N_NODES + 255) / 256;
  const int GW = (N_NODES + 3) / 4;  // one wave per node

  // CSR build
  hipMemsetAsync(deg, 0, (size_t)N_NODES * 4, stream);
  hipLaunchKernelGGL(k_degree, dim3(GE), dim3(256), 0, stream, col, deg, N_EDGES);
  hipLaunchKernelGGL(k_scan1, dim3(NB_SCAN), dim3(256), 0, stream, deg, rowptr, bsum, N_NODES);
  hipLaunchKernelGGL(k_scan2, dim3(1), dim3(256), 0, stream, bsum, NB_SCAN);
  hipLaunchKernelGGL(k_scan3, dim3(GN), dim3(256), 0, stream, rowptr, bsum, N_NODES);
  hipLaunchKernelGGL(k_fill, dim3(GE), dim3(256), 0, stream, row, col, ew, rowptr, csr_row, csr_w, N_EDGES);

  // normalization (two-stage)
  hipLaunchKernelGGL(k_cs1, dim3(RB), dim3(256), 0, stream, x, pcs, N_NODES);
  hipLaunchKernelGGL(k_cs2, dim3(1), dim3(256), 0, stream, pcs, red);
  hipLaunchKernelGGL(k_norm, dim3((N_NODES * 3 + 255) / 256), dim3(256), 0, stream, x, red, x0, N_NODES);

  // layer 1: 3 -> 32|32
  hipLaunchKernelGGL(k_gather3, dim3(GN), dim3(256), 0, stream,
                     x0, rowptr, csr_row, csr_w, gin1_eps, agg1, N_NODES);
  hipLaunchKernelGGL(k_node1, dim3(GN), dim3(256), 0, stream,
                     agg1, h1, gcn1_w, gcn1_b, gin1_w1, gin1_b1, gin1_w2, gin1_b2, N_NODES);

  // layer 2: 64 -> 64|64
  hipLaunchKernelGGL((k_spmmb<64>), dim3(GW), dim3(256), 0, stream,
                     h1, A2, rowptr, csr_row, csr_w, gin2_eps, N_NODES);
  hipLaunchKernelGGL((k_nodeM<64, 64>), dim3(512), dim3(256), 0, stream,
                     A2, h2, gcn2_w, gcn2_b, gin2_w1, gin2_b1, gin2_w2, gin2_b2, N_NODES);

  // layer 3: 128 -> 128|128
  hipLaunchKernelGGL((k_spmmb<128>), dim3(GW), dim3(256), 0, stream,
                     h2, A3, rowptr, csr_row, csr_w, gin3_eps, N_NODES);
  hipLaunchKernelGGL((k_nodeM<128, 128>), dim3(512), dim3(256), 0, stream,
                     A3, h3, gcn3_w, gcn3_b, gin3_w1, gin3_b1, gin3_w2, gin3_b2, N_NODES);

  // GAT (two-stage max + partial sumexp)
  hipLaunchKernelGGL(k_hjb, dim3(GW), dim3(256), 0, stream, h3, gat_w, hj, N_NODES);
  hipLaunchKernelGGL(k_em1, dim3(RB), dim3(256), 0, stream, row, hj, gat_att, pem, N_EDGES);
  hipLaunchKernelGGL(k_em2, dim3(1), dim3(256), 0, stream, pem, red);
  hipLaunchKernelGGL(k_gat, dim3(RB), dim3(256), 0, stream,
                     rowptr, csr_row, hj, gat_att, red, scat, pga, N_NODES);
  hipLaunchKernelGGL(k_gsum, dim3(1), dim3(256), 0, stream, pga, red);

  // pool + readout
  hipLaunchKernelGGL(k_pool, dim3(NGRAPH), dim3(256), 0, stream,
                     h3, scat, red, lin_w, lin_b, lin2_w, lin2_b, out, NGRAPH);
}

// Round 7
// 480.221 us; speedup vs baseline: 6.0285x; 1.0255x over previous
//
#include <hip/hip_runtime.h>
#include <hip/hip_bf16.h>
#include <math.h>

constexpr int N_NODES = 150000;
constexpr int N_EDGES = 1200000;
constexpr int NPGC    = 30;
constexpr int NGRAPH  = N_NODES / NPGC;
constexpr int NB_SCAN = (N_NODES + 1023) / 1024;
constexpr int RB_CS   = 256;    // colstats stage-1 blocks
constexpr int RB_GAT  = 1024;   // em1 / gat grids (4 blocks/CU)

typedef unsigned int u32;
typedef unsigned short u16;
typedef __attribute__((ext_vector_type(8))) short bf16x8;
typedef __attribute__((ext_vector_type(4))) float f32x4;

__device__ __forceinline__ float lrelu(float v) { return v > 0.f ? v : 0.2f * v; }
__device__ __forceinline__ float bf2f(u32 h) { return __uint_as_float(h << 16); }
__device__ __forceinline__ u16 f2bf(float f) {
  u32 u = __float_as_uint(f);
  return (u16)((u + 0x7FFFu + ((u >> 16) & 1u)) >> 16);
}
__device__ __forceinline__ void unpack8(uint4 v, float* f) {
  f[0] = bf2f(v.x & 0xffff); f[1] = bf2f(v.x >> 16);
  f[2] = bf2f(v.y & 0xffff); f[3] = bf2f(v.y >> 16);
  f[4] = bf2f(v.z & 0xffff); f[5] = bf2f(v.z >> 16);
  f[6] = bf2f(v.w & 0xffff); f[7] = bf2f(v.w >> 16);
}

// ---------------- CSR build ----------------

__global__ void k_degree(const int* __restrict__ col, int* __restrict__ deg, int ne) {
  int e = blockIdx.x * 256 + threadIdx.x;
  if (e < ne) atomicAdd(&deg[col[e]], 1);
}

__global__ __launch_bounds__(256) void k_scan1(const int* __restrict__ deg,
                                               int* __restrict__ rowptr,
                                               int* __restrict__ bsum, int n) {
  __shared__ int ts[256];
  int b = blockIdx.x, tid = threadIdx.x;
  int base = b * 1024 + tid * 4;
  int d[4]; int s = 0;
  #pragma unroll
  for (int k = 0; k < 4; ++k) { d[k] = (base + k < n) ? deg[base + k] : 0; s += d[k]; }
  ts[tid] = s;
  __syncthreads();
  for (int off = 1; off < 256; off <<= 1) {
    int v = (tid >= off) ? ts[tid - off] : 0;
    __syncthreads();
    ts[tid] += v;
    __syncthreads();
  }
  int run = ts[tid] - s;
  #pragma unroll
  for (int k = 0; k < 4; ++k) {
    if (base + k < n) rowptr[base + k] = run;
    run += d[k];
  }
  if (tid == 255) bsum[b] = ts[255];
}

__global__ __launch_bounds__(256) void k_scan2(int* __restrict__ bsum, int nb) {
  __shared__ int ts[256];
  int tid = threadIdx.x;
  int orig = (tid < nb) ? bsum[tid] : 0;
  ts[tid] = orig;
  __syncthreads();
  for (int off = 1; off < 256; off <<= 1) {
    int v = (tid >= off) ? ts[tid - off] : 0;
    __syncthreads();
    ts[tid] += v;
    __syncthreads();
  }
  if (tid < nb) bsum[tid] = ts[tid] - orig;
}

__global__ void k_scan3(int* __restrict__ rowptr, const int* __restrict__ bsum, int n) {
  int i = blockIdx.x * 256 + threadIdx.x;
  if (i < n) rowptr[i] += bsum[i >> 10];
}

// fill: one 8B interleaved store per edge; rowptr doubles as cursor
__global__ void k_fill(const int* __restrict__ row, const int* __restrict__ col,
                       const float* __restrict__ ew, int* __restrict__ rowptr,
                       uint2* __restrict__ csr_rw, int ne) {
  int e = blockIdx.x * 256 + threadIdx.x;
  if (e >= ne) return;
  int c = col[e];
  int p = atomicAdd(&rowptr[c], 1);
  uint2 v; v.x = (u32)row[e]; v.y = __float_as_uint(ew[e]);
  csr_rw[p] = v;
}

// ---------------- normalization ----------------

__global__ __launch_bounds__(256) void k_cs1(const float* __restrict__ x,
                                             float* __restrict__ pb, int n) {
  __shared__ float ls[4][6];
  float s0 = 0, s1 = 0, s2 = 0;
  float m0 = -INFINITY, m1 = -INFINITY, m2 = -INFINITY;
  for (int i = blockIdx.x * 256 + threadIdx.x; i < n; i += RB_CS * 256) {
    float v0 = x[3 * i], v1 = x[3 * i + 1], v2 = x[3 * i + 2];
    s0 += v0; s1 += v1; s2 += v2;
    m0 = fmaxf(m0, v0); m1 = fmaxf(m1, v1); m2 = fmaxf(m2, v2);
  }
  for (int o = 32; o > 0; o >>= 1) {
    s0 += __shfl_down(s0, o); s1 += __shfl_down(s1, o); s2 += __shfl_down(s2, o);
    m0 = fmaxf(m0, __shfl_down(m0, o));
    m1 = fmaxf(m1, __shfl_down(m1, o));
    m2 = fmaxf(m2, __shfl_down(m2, o));
  }
  int w = threadIdx.x >> 6;
  if ((threadIdx.x & 63) == 0) {
    ls[w][0] = s0; ls[w][1] = s1; ls[w][2] = s2;
    ls[w][3] = m0; ls[w][4] = m1; ls[w][5] = m2;
  }
  __syncthreads();
  if (threadIdx.x == 0) {
    float* o = pb + blockIdx.x * 8;
    o[0] = ls[0][0] + ls[1][0] + ls[2][0] + ls[3][0];
    o[1] = ls[0][1] + ls[1][1] + ls[2][1] + ls[3][1];
    o[2] = ls[0][2] + ls[1][2] + ls[2][2] + ls[3][2];
    o[3] = fmaxf(fmaxf(ls[0][3], ls[1][3]), fmaxf(ls[2][3], ls[3][3]));
    o[4] = fmaxf(fmaxf(ls[0][4], ls[1][4]), fmaxf(ls[2][4], ls[3][4]));
    o[5] = fmaxf(fmaxf(ls[0][5], ls[1][5]), fmaxf(ls[2][5], ls[3][5]));
  }
}

// norm with folded stage-2 reduction of pcs; each block handles 1024 elements
__global__ __launch_bounds__(256) void k_norm(const float* __restrict__ x,
                                              const float* __restrict__ pcs,
                                              float* __restrict__ x0, int n) {
  __shared__ float ls[4][6];
  __shared__ float rs[6];
  int tid = threadIdx.x;
  const float* p = pcs + tid * 8;
  float s0 = p[0], s1 = p[1], s2 = p[2], m0 = p[3], m1 = p[4], m2 = p[5];
  for (int o = 32; o > 0; o >>= 1) {
    s0 += __shfl_down(s0, o); s1 += __shfl_down(s1, o); s2 += __shfl_down(s2, o);
    m0 = fmaxf(m0, __shfl_down(m0, o));
    m1 = fmaxf(m1, __shfl_down(m1, o));
    m2 = fmaxf(m2, __shfl_down(m2, o));
  }
  int w = tid >> 6;
  if ((tid & 63) == 0) {
    ls[w][0] = s0; ls[w][1] = s1; ls[w][2] = s2;
    ls[w][3] = m0; ls[w][4] = m1; ls[w][5] = m2;
  }
  __syncthreads();
  if (tid == 0) {
    float inv_n = 1.0f / (float)N_NODES;
    #pragma unroll
    for (int c = 0; c < 3; ++c) {
      float mean = (ls[0][c] + ls[1][c] + ls[2][c] + ls[3][c]) * inv_n;
      float mx = fmaxf(fmaxf(ls[0][3 + c], ls[1][3 + c]), fmaxf(ls[2][3 + c], ls[3][3 + c]));
      rs[c] = mean;
      rs[3 + c] = 1.0f / (mx - mean);
    }
  }
  __syncthreads();
  #pragma unroll
  for (int q = 0; q < 4; ++q) {
    int i = blockIdx.x * 1024 + q * 256 + tid;
    if (i < n * 3) {
      int c = i % 3;
      x0[i] = (x[i] - rs[c]) * rs[3 + c];
    }
  }
}

// ---------------- layer 1 ----------------

__global__ void k_gather3(const float* __restrict__ x0, const int* __restrict__ rend,
                          const uint2* __restrict__ csr_rw,
                          const float* __restrict__ epsp, float* __restrict__ agg1, int n) {
  int c = blockIdx.x * 256 + threadIdx.x;
  if (c >= n) return;
  int s = (c == 0) ? 0 : rend[c - 1];
  int e = rend[c];
  float a0 = 0, a1 = 0, a2 = 0, b0 = 0, b1 = 0, b2 = 0;
  for (int p = s; p < e; ++p) {
    uint2 ent = csr_rw[p];
    int r = (int)ent.x;
    float w = __uint_as_float(ent.y);
    float v0 = x0[3 * r], v1 = x0[3 * r + 1], v2 = x0[3 * r + 2];
    a0 += v0 * w; a1 += v1 * w; a2 += v2 * w;
    b0 += v0; b1 += v1; b2 += v2;
  }
  float eps1 = 1.0f + epsp[0];
  float* ap = agg1 + (size_t)c * 8;
  ap[0] = a0; ap[1] = a1; ap[2] = a2;
  ap[3] = eps1 * x0[3 * c] + b0;
  ap[4] = eps1 * x0[3 * c + 1] + b1;
  ap[5] = eps1 * x0[3 * c + 2] + b2;
}

__global__ __launch_bounds__(256) void k_node1(
    const float* __restrict__ agg1, u16* __restrict__ h1,
    const float* __restrict__ gw, const float* __restrict__ gb,
    const float* __restrict__ w1, const float* __restrict__ b1,
    const float* __restrict__ w2, const float* __restrict__ b2, int n) {
  __shared__ float Ws[96], W1s[30], W2s[320], GBs[32], B1s[10], B2s[32];
  int tid = threadIdx.x;
  if (tid < 96) Ws[tid] = gw[tid];
  if (tid < 30) W1s[tid] = w1[tid];
  for (int i = tid; i < 320; i += 256) W2s[i] = w2[i];
  if (tid < 32) { GBs[tid] = gb[tid]; B2s[tid] = b2[tid]; }
  if (tid < 10) B1s[tid] = b1[tid];
  __syncthreads();
  int nd = blockIdx.x * 256 + tid;
  if (nd >= n) return;
  const float* a = agg1 + (size_t)nd * 8;
  float a0 = a[0], a1 = a[1], a2 = a[2], m0 = a[3], m1 = a[4], m2 = a[5];
  float t[10];
  #pragma unroll
  for (int h = 0; h < 10; ++h)
    t[h] = fmaxf(B1s[h] + m0 * W1s[h] + m1 * W1s[10 + h] + m2 * W1s[20 + h], 0.f);
  u32 w_[32];
  #pragma unroll
  for (int j = 0; j < 32; ++j) {
    float v = lrelu(GBs[j] + a0 * Ws[j] + a1 * Ws[32 + j] + a2 * Ws[64 + j]);
    u32 bv = f2bf(v);
    if (j & 1) w_[j >> 1] |= bv << 16; else w_[j >> 1] = bv;
  }
  #pragma unroll
  for (int j = 0; j < 32; ++j) {
    float s = B2s[j];
    #pragma unroll
    for (int h = 0; h < 10; ++h) s += t[h] * W2s[h * 32 + j];
    u32 bv = f2bf(fmaxf(s, 0.f));
    int jj = 32 + j;
    if (jj & 1) w_[jj >> 1] |= bv << 16; else w_[jj >> 1] = bv;
  }
  uint4* dst = (uint4*)(h1 + (size_t)nd * 64);
  #pragma unroll
  for (int q = 0; q < 8; ++q) {
    uint4 v; v.x = w_[q * 4]; v.y = w_[q * 4 + 1]; v.z = w_[q * 4 + 2]; v.w = w_[q * 4 + 3];
    dst[q] = v;
  }
}

// ---------------- bf16 edge-parallel SpMM ----------------

template <int FIN>
__global__ __launch_bounds__(256) void k_spmmb(
    const u16* __restrict__ hp, u16* __restrict__ Aout,
    const int* __restrict__ rend, const uint2* __restrict__ csr_rw,
    const float* __restrict__ epsp, int n) {
  constexpr int LPF = FIN / 8;
  constexpr int EG  = 64 / LPF;
  int wid = (blockIdx.x * 256 + threadIdx.x) >> 6;
  if (wid >= n) return;
  int lane = threadIdx.x & 63;
  int fl = lane & (LPF - 1);
  int eg = lane / LPF;
  int s = (wid == 0) ? 0 : rend[wid - 1];
  int e = rend[wid];
  float aa[8] = {0, 0, 0, 0, 0, 0, 0, 0};
  float bb[8] = {0, 0, 0, 0, 0, 0, 0, 0};
  for (int p = s + eg; p < e; p += EG) {
    uint2 ent = csr_rw[p];
    int r = (int)ent.x;
    float w = __uint_as_float(ent.y);
    uint4 v = *(const uint4*)(hp + (size_t)r * FIN + fl * 8);
    float f[8]; unpack8(v, f);
    #pragma unroll
    for (int i = 0; i < 8; ++i) { aa[i] += f[i] * w; bb[i] += f[i]; }
  }
  #pragma unroll
  for (int off = LPF; off < 64; off <<= 1) {
    #pragma unroll
    for (int i = 0; i < 8; ++i) {
      aa[i] += __shfl_xor(aa[i], off);
      bb[i] += __shfl_xor(bb[i], off);
    }
  }
  if (eg == 0) {
    float eps1 = 1.0f + epsp[0];
    uint4 hv = *(const uint4*)(hp + (size_t)wid * FIN + fl * 8);
    float hm[8]; unpack8(hv, hm);
    uint4 pa, pm;
    float m[8];
    #pragma unroll
    for (int i = 0; i < 8; ++i) m[i] = eps1 * hm[i] + bb[i];
    pa.x = f2bf(aa[0]) | ((u32)f2bf(aa[1]) << 16);
    pa.y = f2bf(aa[2]) | ((u32)f2bf(aa[3]) << 16);
    pa.z = f2bf(aa[4]) | ((u32)f2bf(aa[5]) << 16);
    pa.w = f2bf(aa[6]) | ((u32)f2bf(aa[7]) << 16);
    pm.x = f2bf(m[0]) | ((u32)f2bf(m[1]) << 16);
    pm.y = f2bf(m[2]) | ((u32)f2bf(m[3]) << 16);
    pm.z = f2bf(m[4]) | ((u32)f2bf(m[5]) << 16);
    pm.w = f2bf(m[6]) | ((u32)f2bf(m[7]) << 16);
    *(uint4*)(Aout + (size_t)wid * (2 * FIN) + fl * 8) = pa;
    *(uint4*)(Aout + (size_t)wid * (2 * FIN) + FIN + fl * 8) = pm;
  }
}

// ---------------- MFMA node update ----------------

template <int FIN, int FOUT>
__global__ __launch_bounds__(256) void k_nodeM(
    const u16* __restrict__ Ain, u16* __restrict__ ho,
    const float* __restrict__ gw, const float* __restrict__ gb,
    const float* __restrict__ w1, const float* __restrict__ b1,
    const float* __restrict__ w2, const float* __restrict__ b2, int n) {
  constexpr int AST = 2 * FIN;
  constexpr int HST = 2 * FOUT;
  constexpr int NKS = FIN / 32;
  constexpr int NJT = FOUT / 16;
  __shared__ __align__(16) u16 Wt[FOUT * FIN];
  __shared__ __align__(16) u16 W1t[16 * FIN];
  __shared__ __align__(16) u16 W2t[FOUT * 32];
  __shared__ __align__(16) u16 Tl[4][16][32];
  __shared__ float GBs[FOUT], B1s[16], B2s[FOUT];
  const int tid = threadIdx.x;
  for (int i = tid; i < FOUT * FIN; i += 256) {
    int j = i / FIN, k = i - j * FIN;
    Wt[i] = f2bf(gw[k * FOUT + j]);
  }
  for (int i = tid; i < 16 * FIN; i += 256) {
    int h = i / FIN, k = i - h * FIN;
    W1t[i] = (h < 10) ? f2bf(w1[k * 10 + h]) : (u16)0;
  }
  for (int i = tid; i < FOUT * 32; i += 256) {
    int j = i >> 5, k = i & 31;
    W2t[i] = (k < 10) ? f2bf(w2[k * FOUT + j]) : (u16)0;
  }
  for (int i = tid; i < FOUT; i += 256) { GBs[i] = gb[i]; B2s[i] = b2[i]; }
  if (tid < 16) B1s[tid] = (tid < 10) ? b1[tid] : 0.f;
  for (int i = tid; i < 4 * 16 * 32; i += 256) ((u16*)Tl)[i] = 0;
  __syncthreads();
  const int wid = tid >> 6, lane = tid & 63;
  const int c16 = lane & 15, kg = lane >> 4;
  const int ntile = n >> 4;
  for (int t = blockIdx.x * 4 + wid; t < ntile; t += gridDim.x * 4) {
    const int nb = t << 4;
    const u16* arow = Ain + (size_t)(nb + c16) * AST;
    bf16x8 aA[NKS], aM[NKS];
    #pragma unroll
    for (int ks = 0; ks < NKS; ++ks) {
      aA[ks] = *(const bf16x8*)(arow + ks * 32 + kg * 8);
      aM[ks] = *(const bf16x8*)(arow + FIN + ks * 32 + kg * 8);
    }
    f32x4 tacc = {0.f, 0.f, 0.f, 0.f};
    #pragma unroll
    for (int ks = 0; ks < NKS; ++ks) {
      bf16x8 b = *(const bf16x8*)&W1t[c16 * FIN + ks * 32 + kg * 8];
      tacc = __builtin_amdgcn_mfma_f32_16x16x32_bf16(aM[ks], b, tacc, 0, 0, 0);
    }
    #pragma unroll
    for (int r = 0; r < 4; ++r)
      Tl[wid][kg * 4 + r][c16] = f2bf(fmaxf(tacc[r] + B1s[c16], 0.f));
    __builtin_amdgcn_sched_barrier(0);
    #pragma unroll
    for (int jt = 0; jt < NJT; ++jt) {
      f32x4 acc = {0.f, 0.f, 0.f, 0.f};
      #pragma unroll
      for (int ks = 0; ks < NKS; ++ks) {
        bf16x8 b = *(const bf16x8*)&Wt[(jt * 16 + c16) * FIN + ks * 32 + kg * 8];
        acc = __builtin_amdgcn_mfma_f32_16x16x32_bf16(aA[ks], b, acc, 0, 0, 0);
      }
      int colj = jt * 16 + c16;
      #pragma unroll
      for (int r = 0; r < 4; ++r) {
        int nd = nb + kg * 4 + r;
        ho[(size_t)nd * HST + colj] = f2bf(lrelu(acc[r] + GBs[colj]));
      }
    }
    bf16x8 at = *(const bf16x8*)&Tl[wid][c16][kg * 8];
    #pragma unroll
    for (int jt = 0; jt < NJT; ++jt) {
      f32x4 acc = {0.f, 0.f, 0.f, 0.f};
      bf16x8 b = *(const bf16x8*)&W2t[(jt * 16 + c16) * 32 + kg * 8];
      acc = __builtin_amdgcn_mfma_f32_16x16x32_bf16(at, b, acc, 0, 0, 0);
      int colj = jt * 16 + c16;
      #pragma unroll
      for (int r = 0; r < 4; ++r) {
        int nd = nb + kg * 4 + r;
        ho[(size_t)nd * HST + FOUT + colj] = f2bf(fmaxf(acc[r] + B2s[colj], 0.f));
      }
    }
  }
}

// ---------------- GAT + pool ----------------

__global__ __launch_bounds__(256) void k_hjb(const u16* __restrict__ h3,
                                             const float* __restrict__ gw,
                                             float* __restrict__ hj, int n) {
  int wid = blockIdx.x * 4 + (threadIdx.x >> 6);
  if (wid >= n) return;
  int lane = threadIdx.x & 63;
  const u16* r = h3 + (size_t)wid * 256 + lane * 4;
  uint2 v = *(const uint2*)r;
  float acc = bf2f(v.x & 0xffff) * gw[lane * 4] + bf2f(v.x >> 16) * gw[lane * 4 + 1] +
              bf2f(v.y & 0xffff) * gw[lane * 4 + 2] + bf2f(v.y >> 16) * gw[lane * 4 + 3];
  for (int o = 32; o > 0; o >>= 1) acc += __shfl_down(acc, o);
  if (lane == 0) hj[wid] = acc;
}

__global__ __launch_bounds__(256) void k_em1(const int* __restrict__ row,
                                             const float* __restrict__ hj,
                                             const float* __restrict__ att,
                                             float* __restrict__ pb, int ne) {
  __shared__ float ls[4];
  float a = att[0];
  float m = -INFINITY;
  for (int e = blockIdx.x * 256 + threadIdx.x; e < ne; e += RB_GAT * 256) {
    m = fmaxf(m, lrelu(a * hj[row[e]]));
  }
  for (int o = 32; o > 0; o >>= 1) m = fmaxf(m, __shfl_down(m, o));
  int w = threadIdx.x >> 6;
  if ((threadIdx.x & 63) == 0) ls[w] = m;
  __syncthreads();
  if (threadIdx.x == 0)
    pb[blockIdx.x] = fmaxf(fmaxf(ls[0], ls[1]), fmaxf(ls[2], ls[3]));
}

// gat with folded stage-2 max (reduces pem[RB_GAT]) + per-block partial sumexp
__global__ __launch_bounds__(256) void k_gat(const int* __restrict__ rend,
                                             const uint2* __restrict__ csr_rw,
                                             const float* __restrict__ hj,
                                             const float* __restrict__ att,
                                             const float* __restrict__ pem,
                                             float* __restrict__ scat,
                                             float* __restrict__ pga, int n) {
  __shared__ float ls[4];
  __shared__ float msh;
  int tid = threadIdx.x;
  float m = fmaxf(fmaxf(pem[tid], pem[tid + 256]),
                  fmaxf(pem[tid + 512], pem[tid + 768]));
  for (int o = 32; o > 0; o >>= 1) m = fmaxf(m, __shfl_down(m, o));
  int w = tid >> 6;
  if ((tid & 63) == 0) ls[w] = m;
  __syncthreads();
  if (tid == 0) msh = fmaxf(fmaxf(ls[0], ls[1]), fmaxf(ls[2], ls[3]));
  __syncthreads();
  m = msh;
  float a = att[0];
  float lsum = 0.f;
  for (int c = blockIdx.x * 256 + tid; c < n; c += RB_GAT * 256) {
    int s = (c == 0) ? 0 : rend[c - 1];
    int e = rend[c];
    float acc = 0.f;
    for (int p = s; p < e; ++p) {
      float h = hj[(int)csr_rw[p].x];
      float pex = expf(lrelu(a * h) - m);
      lsum += pex;
      acc += pex * h;
    }
    scat[c] = acc;
  }
  __syncthreads();
  for (int o = 32; o > 0; o >>= 1) lsum += __shfl_down(lsum, o);
  if ((tid & 63) == 0) ls[w] = lsum;
  __syncthreads();
  if (tid == 0) pga[blockIdx.x] = ls[0] + ls[1] + ls[2] + ls[3];
}

// pool with folded sumexp reduction of pga[RB_GAT]
__global__ __launch_bounds__(256) void k_pool(
    const u16* __restrict__ h3, const float* __restrict__ scat,
    const float* __restrict__ pga,
    const float* __restrict__ lw, const float* __restrict__ lb,
    const float* __restrict__ l2w, const float* __restrict__ l2b,
    float* __restrict__ out, int ng) {
  __shared__ float ls[4];
  __shared__ float pooled[256];
  __shared__ float aw[NPGC];
  __shared__ float y[10];
  int g = blockIdx.x;
  if (g >= ng) return;
  int tid = threadIdx.x;
  float s = pga[tid] + pga[tid + 256] + pga[tid + 512] + pga[tid + 768];
  for (int o = 32; o > 0; o >>= 1) s += __shfl_down(s, o);
  int w = tid >> 6;
  if ((tid & 63) == 0) ls[w] = s;
  __syncthreads();
  float inv_sexp = 1.0f / (ls[0] + ls[1] + ls[2] + ls[3]);
  if (tid < NPGC) aw[tid] = scat[g * NPGC + tid] * inv_sexp;
  __syncthreads();
  const u16* base = h3 + (size_t)g * NPGC * 256;
  float acc = 0.f;
  #pragma unroll
  for (int u = 0; u < NPGC; ++u) acc += bf2f(base[u * 256 + tid]) * aw[u];
  pooled[tid] = acc * (1.0f / NPGC);
  __syncthreads();
  if (tid < 10) {
    float sy = lb[tid];
    for (int f = 0; f < 256; ++f) sy += pooled[f] * lw[f * 10 + tid];
    y[tid] = sy;
  }
  __syncthreads();
  if (tid == 0) {
    float sy = l2b[0];
    #pragma unroll
    for (int k = 0; k < 10; ++k) sy += y[k] * l2w[k];
    out[g] = 1.0f / (1.0f + expf(-sy));
  }
}

extern "C" void kernel_launch(void* const* d_in, const int* in_sizes, int n_in,
                              void* d_out, int out_size, void* d_ws, size_t ws_size,
                              hipStream_t stream) {
  const float* x        = (const float*)d_in[0];
  const int*   eidx     = (const int*)d_in[1];
  const float* ew       = (const float*)d_in[2];
  const float* gcn1_w   = (const float*)d_in[3];
  const float* gcn1_b   = (const float*)d_in[4];
  const float* gcn2_w   = (const float*)d_in[5];
  const float* gcn2_b   = (const float*)d_in[6];
  const float* gcn3_w   = (const float*)d_in[7];
  const float* gcn3_b   = (const float*)d_in[8];
  const float* gin1_w1  = (const float*)d_in[9];
  const float* gin1_b1  = (const float*)d_in[10];
  const float* gin1_w2  = (const float*)d_in[11];
  const float* gin1_b2  = (const float*)d_in[12];
  const float* gin1_eps = (const float*)d_in[13];
  const float* gin2_w1  = (const float*)d_in[14];
  const float* gin2_b1  = (const float*)d_in[15];
  const float* gin2_w2  = (const float*)d_in[16];
  const float* gin2_b2  = (const float*)d_in[17];
  const float* gin2_eps = (const float*)d_in[18];
  const float* gin3_w1  = (const float*)d_in[19];
  const float* gin3_b1  = (const float*)d_in[20];
  const float* gin3_w2  = (const float*)d_in[21];
  const float* gin3_b2  = (const float*)d_in[22];
  const float* gin3_eps = (const float*)d_in[23];
  const float* gat_w    = (const float*)d_in[24];
  const float* gat_att  = (const float*)d_in[25];
  const float* lin_w    = (const float*)d_in[26];
  const float* lin_b    = (const float*)d_in[27];
  const float* lin2_w   = (const float*)d_in[28];
  const float* lin2_b   = (const float*)d_in[29];
  float* out = (float*)d_out;

  const int* row = eidx;
  const int* col = eidx + N_EDGES;

  // Workspace (bytes), peak ~203 MB:
  //  R1 [N*512 B]: {x0 f32 N*3 | agg1 f32 N*8 | h1 bf16 N*64} -> A3 bf16 N*256
  //  R2 [N*512 B]: {deg,bsum} -> A2 bf16 N*128 -> h3 bf16 N*256
  //  R3 [N*256 B]: h2 bf16 N*128 -> {hj f32 N | scat f32 N}
  //  persistent: rowptr[N], csr_rw uint2[E], pcs[RB_CS*8], pem[RB_GAT], pga[RB_GAT]
  char* B = (char*)d_ws;
  float* x0     = (float*)B;
  float* agg1   = (float*)(B + (size_t)N_NODES * 12);
  u16*   h1     = (u16*)(B + (size_t)N_NODES * 44);
  u16*   A3     = (u16*)B;
  u16*   A2     = (u16*)(B + (size_t)N_NODES * 512);
  u16*   h3     = (u16*)(B + (size_t)N_NODES * 512);
  int*   deg    = (int*)(B + (size_t)N_NODES * 512);
  int*   bsum   = deg + N_NODES;
  u16*   h2     = (u16*)(B + (size_t)N_NODES * 1024);
  float* hj     = (float*)(B + (size_t)N_NODES * 1024);
  float* scat   = hj + N_NODES;
  int*   rowptr = (int*)(B + (size_t)N_NODES * 1280);
  uint2* csr_rw = (uint2*)(rowptr + N_NODES);
  float* pcs    = (float*)(csr_rw + N_EDGES);   // RB_CS*8
  float* pem    = pcs + RB_CS * 8;              // RB_GAT
  float* pga    = pem + RB_GAT;                 // RB_GAT

  const int GE = (N_EDGES + 255) / 256;
  const int GN = (N_NODES + 255) / 256;
  const int GW = (N_NODES + 3) / 4;

  // CSR build
  hipMemsetAsync(deg, 0, (size_t)N_NODES * 4, stream);
  hipLaunchKernelGGL(k_degree, dim3(GE), dim3(256), 0, stream, col, deg, N_EDGES);
  hipLaunchKernelGGL(k_scan1, dim3(NB_SCAN), dim3(256), 0, stream, deg, rowptr, bsum, N_NODES);
  hipLaunchKernelGGL(k_scan2, dim3(1), dim3(256), 0, stream, bsum, NB_SCAN);
  hipLaunchKernelGGL(k_scan3, dim3(GN), dim3(256), 0, stream, rowptr, bsum, N_NODES);
  hipLaunchKernelGGL(k_fill, dim3(GE), dim3(256), 0, stream, row, col, ew, rowptr, csr_rw, N_EDGES);

  // normalization
  hipLaunchKernelGGL(k_cs1, dim3(RB_CS), dim3(256), 0, stream, x, pcs, N_NODES);
  hipLaunchKernelGGL(k_norm, dim3((N_NODES * 3 + 1023) / 1024), dim3(256), 0, stream, x, pcs, x0, N_NODES);

  // layer 1: 3 -> 32|32
  hipLaunchKernelGGL(k_gather3, dim3(GN), dim3(256), 0, stream,
                     x0, rowptr, csr_rw, gin1_eps, agg1, N_NODES);
  hipLaunchKernelGGL(k_node1, dim3(GN), dim3(256), 0, stream,
                     agg1, h1, gcn1_w, gcn1_b, gin1_w1, gin1_b1, gin1_w2, gin1_b2, N_NODES);

  // layer 2: 64 -> 64|64
  hipLaunchKernelGGL((k_spmmb<64>), dim3(GW), dim3(256), 0, stream,
                     h1, A2, rowptr, csr_rw, gin2_eps, N_NODES);
  hipLaunchKernelGGL((k_nodeM<64, 64>), dim3(512), dim3(256), 0, stream,
                     A2, h2, gcn2_w, gcn2_b, gin2_w1, gin2_b1, gin2_w2, gin2_b2, N_NODES);

  // layer 3: 128 -> 128|128
  hipLaunchKernelGGL((k_spmmb<128>), dim3(GW), dim3(256), 0, stream,
                     h2, A3, rowptr, csr_rw, gin3_eps, N_NODES);
  hipLaunchKernelGGL((k_nodeM<128, 128>), dim3(512), dim3(256), 0, stream,
                     A3, h3, gcn3_w, gcn3_b, gin3_w1, gin3_b1, gin3_w2, gin3_b2, N_NODES);

  // GAT
  hipLaunchKernelGGL(k_hjb, dim3(GW), dim3(256), 0, stream, h3, gat_w, hj, N_NODES);
  hipLaunchKernelGGL(k_em1, dim3(RB_GAT), dim3(256), 0, stream, row, hj, gat_att, pem, N_EDGES);
  hipLaunchKernelGGL(k_gat, dim3(RB_GAT), dim3(256), 0, stream,
                     rowptr, csr_rw, hj, gat_att, pem, scat, pga, N_NODES);

  // pool + readout
  hipLaunchKernelGGL(k_pool, dim3(NGRAPH), dim3(256), 0, stream,
                     h3, scat, pga, lin_w, lin_b, lin2_w, lin2_b, out, NGRAPH);
}